// Round 1
// baseline (278.831 us; speedup 1.0000x reference)
//
#include <hip/hip_runtime.h>
#include <hip/hip_bf16.h>
#include <math.h>

#define DI __device__ __forceinline__

typedef __bf16 bf16x8 __attribute__((ext_vector_type(8)));
typedef float  f32x4  __attribute__((ext_vector_type(4)));

static constexpr int   Bsz  = 2, Ssz = 4096, Hsz = 2048, Dsz = 128;
static constexpr int   Nrow = Bsz * Ssz;     // 8192
static constexpr int   CH   = 128;           // chunk length
static constexpr int   NCH  = Nrow / CH;     // 64 chunks total
static constexpr int   CPB  = Ssz / CH;      // 32 chunks per batch
static constexpr float EPSF = 1e-6f;

// ---------------- workspace layout (bytes) ----------------
static constexpr size_t WQKV_OFF  = 0;                                    // bf16 [384][2048]
static constexpr size_t WO_OFF    = WQKV_OFF + (size_t)384*2048*2;        // bf16 [2048][128]
static constexpr size_t MB_OFF    = WO_OFF   + (size_t)2048*128*2;        // bf16 [128][128]
static constexpr size_t QB_OFF    = MB_OFF   + (size_t)128*128*2;         // bf16 [8192][128]
static constexpr size_t KB_OFF    = QB_OFF   + (size_t)Nrow*Dsz*2;
static constexpr size_t VB_OFF    = KB_OFF   + (size_t)Nrow*Dsz*2;
static constexpr size_t P_OFF     = VB_OFF   + (size_t)Nrow*Dsz*2;        // bf16 [8192][128]
static constexpr size_t KV_OFF    = P_OFF    + (size_t)Nrow*Dsz*2;        // f32 [64][128][128]
static constexpr size_t KVPRE_OFF = KV_OFF   + (size_t)NCH*Dsz*Dsz*4;
static constexpr size_t KSUM_OFF  = KVPRE_OFF+ (size_t)NCH*Dsz*Dsz*4;     // f32 [64][128]
static constexpr size_t KPRE_OFF  = KSUM_OFF + (size_t)NCH*Dsz*4;
static constexpr size_t MPART_OFF = KPRE_OFF + (size_t)NCH*Dsz*4;         // f32 [64][128][128]
static constexpr size_t LI_OFF    = MPART_OFF+ (size_t)NCH*Dsz*Dsz*4;     // f32 [8192][128]
static constexpr size_t PM_OFF    = LI_OFF   + (size_t)Nrow*Dsz*4;        // f32 [8192][128]
static constexpr size_t DLOC_OFF  = PM_OFF   + (size_t)Nrow*Dsz*4;        // f32 [8192]

// ---------------- helpers ----------------
DI float b2f(unsigned short u) {
    union { float f; unsigned int i; } x; x.i = ((unsigned int)u) << 16; return x.f;
}
DI unsigned short f2b(float f) {
    __bf16 h = (__bf16)f; return __builtin_bit_cast(unsigned short, h);
}
DI float sig_elu(float x) { return x > 0.f ? x + 1.f : expf(x); }

DI f32x4 MFMA(bf16x8 a, bf16x8 b, f32x4 c) {
    return __builtin_amdgcn_mfma_f32_16x16x32_bf16(a, b, c, 0, 0, 0);
}

DI void zacc(f32x4 (&acc)[4][4]) {
    f32x4 zz = {0.f, 0.f, 0.f, 0.f};
    #pragma unroll
    for (int i = 0; i < 4; i++)
        #pragma unroll
        for (int j = 0; j < 4; j++) acc[i][j] = zz;
}

// 128x128 (MxN), K=128 matmul out of LDS operands in the canonical frag layout.
// Operand layout: elem (r,k) lives at ((k>>3)*128 + r)*8 + (k&7)  (ushort index)
DI void mm128(const unsigned short* A, const unsigned short* Bm, f32x4 (&acc)[4][4],
              int wm, int wn, int quad, int lr) {
    #pragma unroll
    for (int ks = 0; ks < 4; ks++) {
        bf16x8 a[4], b[4];
        #pragma unroll
        for (int mb = 0; mb < 4; mb++)
            a[mb] = *(const bf16x8*)&A[(size_t)((ks*4 + quad)*128 + wm*64 + mb*16 + lr)*8];
        #pragma unroll
        for (int nb = 0; nb < 4; nb++)
            b[nb] = *(const bf16x8*)&Bm[(size_t)((ks*4 + quad)*128 + wn*64 + nb*16 + lr)*8];
        #pragma unroll
        for (int mb = 0; mb < 4; mb++)
            #pragma unroll
            for (int nb = 0; nb < 4; nb++)
                acc[mb][nb] = MFMA(a[mb], b[nb], acc[mb][nb]);
    }
}

// direct copy of a row-major [128][128] bf16 tile into operand layout
DI void stage_direct(unsigned short* dst, const unsigned short* src, int src_ld, int tid) {
    #pragma unroll
    for (int i = 0; i < 8; i++) {
        int s = tid + i*256; int r = s >> 4, kc = s & 15;
        *(uint4*)&dst[(size_t)(kc*128 + r)*8] = *(const uint4*)(src + (size_t)r*src_ld + kc*8);
    }
}

// transposed staging: dst operand elem (r=col, k=row) <- src[row][col]
DI void stage_T(unsigned short* dst, const unsigned short* src, int src_ld, int tid) {
    #pragma unroll
    for (int i = 0; i < 8; i++) {
        int s = tid + i*256; int rw = s >> 4, c0 = (s & 15)*8;
        unsigned short tmp[8];
        *(uint4*)tmp = *(const uint4*)(src + (size_t)rw*src_ld + c0);
        #pragma unroll
        for (int j = 0; j < 8; j++)
            dst[(size_t)((rw >> 3)*128 + c0 + j)*8 + (rw & 7)] = tmp[j];
    }
}

// ---------------- kernels ----------------
__global__ void k_cvt(const float* __restrict__ s, unsigned short* __restrict__ d, int n) {
    int i = blockIdx.x*256 + threadIdx.x;
    if (i < n) d[i] = f2b(s[i]);
}

// QKV projection: X[8192,2048] fp32 @ Wqkv[384,2048]^T (B^T GEMM), epilogue sigma -> bf16
__global__ __launch_bounds__(256) void k_gemm_qkv(
    const float* __restrict__ X, const unsigned short* __restrict__ W,
    unsigned short* __restrict__ Qb, unsigned short* __restrict__ Kb,
    unsigned short* __restrict__ Vb)
{
    __shared__ unsigned short lA[128*32];
    __shared__ unsigned short lB[128*32];
    const int tid = threadIdx.x;
    const int row0 = blockIdx.x * 128;
    const int ct   = blockIdx.y;          // 0=q 1=k 2=v
    const int n0   = ct * 128;
    const int wave = tid >> 6, lane = tid & 63;
    const int wm = wave >> 1, wn = wave & 1;
    const int quad = lane >> 4, lr = lane & 15;

    f32x4 acc[4][4]; zacc(acc);

    for (int kt = 0; kt < Hsz; kt += 32) {
        // A: 512 slots of 8 bf16; s -> r=s>>2, kc=s&3 (coalesced 32B fp32 reads + inline cvt)
        #pragma unroll
        for (int i = 0; i < 2; i++) {
            int s = tid + i*256; int r = s >> 2, kc = s & 3;
            const float* gp = X + (size_t)(row0 + r)*Hsz + kt + kc*8;
            float4 a0 = *(const float4*)gp;
            float4 a1 = *(const float4*)(gp + 4);
            const float* f0 = (const float*)&a0;
            const float* f1 = (const float*)&a1;
            unsigned short tmp[8];
            #pragma unroll
            for (int j = 0; j < 4; j++) { tmp[j] = f2b(f0[j]); tmp[4+j] = f2b(f1[j]); }
            *(uint4*)&lA[(size_t)(kc*128 + r)*8] = *(const uint4*)tmp;
        }
        // B: bf16 source, direct 16B copy
        #pragma unroll
        for (int i = 0; i < 2; i++) {
            int s = tid + i*256; int r = s >> 2, kc = s & 3;
            *(uint4*)&lB[(size_t)(kc*128 + r)*8] =
                *(const uint4*)(W + (size_t)(n0 + r)*Hsz + kt + kc*8);
        }
        __syncthreads();
        bf16x8 a[4], b[4];
        #pragma unroll
        for (int mb = 0; mb < 4; mb++)
            a[mb] = *(const bf16x8*)&lA[(size_t)(quad*128 + wm*64 + mb*16 + lr)*8];
        #pragma unroll
        for (int nb = 0; nb < 4; nb++)
            b[nb] = *(const bf16x8*)&lB[(size_t)(quad*128 + wn*64 + nb*16 + lr)*8];
        #pragma unroll
        for (int mb = 0; mb < 4; mb++)
            #pragma unroll
            for (int nb = 0; nb < 4; nb++)
                acc[mb][nb] = MFMA(a[mb], b[nb], acc[mb][nb]);
        __syncthreads();
    }

    unsigned short* dst = (ct == 0) ? Qb : (ct == 1 ? Kb : Vb);
    const bool do_sig = (ct < 2);
    #pragma unroll
    for (int mb = 0; mb < 4; mb++)
        #pragma unroll
        for (int nb = 0; nb < 4; nb++)
            #pragma unroll
            for (int rg = 0; rg < 4; rg++) {
                int s_ = wm*64 + mb*16 + quad*4 + rg;
                int e_ = wn*64 + nb*16 + lr;
                float v = acc[mb][nb][rg];
                if (do_sig) v = sig_elu(v);
                dst[(size_t)(row0 + s_)*Dsz + e_] = f2b(v);
            }
}

// Per chunk: v_ret = (K̃@M)/(K̃·z+eps); Mpart_c = K̃^T(V - v_ret); KV_c = K̃^T V; ksum_c = colsum K̃
__global__ __launch_bounds__(256) void k_delta_kv(
    const unsigned short* __restrict__ Kb, const unsigned short* __restrict__ Vb,
    const unsigned short* __restrict__ Mb, const float* __restrict__ z,
    float* __restrict__ KV, float* __restrict__ ksum, float* __restrict__ Mpart)
{
    __shared__ unsigned short b0[128*128];
    __shared__ unsigned short b1[128*128];
    __shared__ float den[128];
    const int tid = threadIdx.x;
    const int c = blockIdx.x, t0 = c*128;
    const int wave = tid >> 6, lane = tid & 63;
    const int wm = wave >> 1, wn = wave & 1, quad = lane >> 4, lr = lane & 15;

    stage_direct(b0, Kb + (size_t)t0*Dsz, Dsz, tid);   // K̃ (A-operand)
    stage_T(b1, Mb, Dsz, tid);                          // M^T (B-operand: B[k=d][n=e]=M[d][e])
    __syncthreads();

    f32x4 acc[4][4]; zacc(acc);
    mm128(b0, b1, acc, wm, wn, quad, lr);               // vret_num[s][e]

    if (tid < 128) {                                    // den[s] = K̃[s]·z + eps
        float p = 0.f;
        for (int d = 0; d < 128; d++)
            p += b2f(b0[(size_t)((d>>3)*128 + tid)*8 + (d&7)]) * z[d];
        den[tid] = p + EPSF;
    }
    __syncthreads();                                    // b0/b1 reads + den done

    stage_T(b1, Kb + (size_t)t0*Dsz, Dsz, tid);         // K̃^T (A-operand: A[m=d][k=t])
    // b0 <- W = V - vret  (B-operand: B[k=t][n=e])
    #pragma unroll
    for (int mb = 0; mb < 4; mb++)
        #pragma unroll
        for (int nb = 0; nb < 4; nb++)
            #pragma unroll
            for (int rg = 0; rg < 4; rg++) {
                int s_ = wm*64 + mb*16 + quad*4 + rg;
                int e_ = wn*64 + nb*16 + lr;
                float v = b2f(Vb[(size_t)(t0 + s_)*Dsz + e_]);
                float w = v - acc[mb][nb][rg] / den[s_];
                b0[(size_t)((s_>>3)*128 + e_)*8 + (s_&7)] = f2b(w);
            }
    __syncthreads();

    if (tid < 128) {                                    // ksum_c[d] = sum_t K̃[t,d]
        float p = 0.f;
        for (int t = 0; t < 128; t++)
            p += b2f(b1[(size_t)((t>>3)*128 + tid)*8 + (t&7)]);
        ksum[(size_t)c*128 + tid] = p;
    }
    f32x4 acc2[4][4]; zacc(acc2);
    mm128(b1, b0, acc2, wm, wn, quad, lr);              // Mpart = K̃^T @ W
    #pragma unroll
    for (int mb = 0; mb < 4; mb++)
        #pragma unroll
        for (int nb = 0; nb < 4; nb++)
            #pragma unroll
            for (int rg = 0; rg < 4; rg++) {
                int d_ = wm*64 + mb*16 + quad*4 + rg;
                int e_ = wn*64 + nb*16 + lr;
                Mpart[(size_t)c*16384 + (size_t)d_*128 + e_] = acc2[mb][nb][rg];
            }
    __syncthreads();

    stage_T(b0, Vb + (size_t)t0*Dsz, Dsz, tid);         // V^T (B-operand: B[k=t][n=e])
    __syncthreads();

    f32x4 acc3[4][4]; zacc(acc3);
    mm128(b1, b0, acc3, wm, wn, quad, lr);              // KV_c = K̃^T @ V
    #pragma unroll
    for (int mb = 0; mb < 4; mb++)
        #pragma unroll
        for (int nb = 0; nb < 4; nb++)
            #pragma unroll
            for (int rg = 0; rg < 4; rg++) {
                int d_ = wm*64 + mb*16 + quad*4 + rg;
                int e_ = wn*64 + nb*16 + lr;
                KV[(size_t)c*16384 + (size_t)d_*128 + e_] = acc3[mb][nb][rg];
            }
}

// exclusive prefix over chunks (per batch) of KV and ksum
__global__ void k_prefix(const float* __restrict__ KV, const float* __restrict__ ksum,
                         float* __restrict__ KVpre, float* __restrict__ kpre)
{
    int idx = blockIdx.x*256 + threadIdx.x;
    if (idx >= 2*16512) return;
    int batch = idx / 16512, e = idx % 16512;
    if (e < 16384) {
        float a = 0.f;
        for (int i = 0; i < CPB; i++) {
            int cc = batch*CPB + i;
            KVpre[(size_t)cc*16384 + e] = a;
            a += KV[(size_t)cc*16384 + e];
        }
    } else {
        int d = e - 16384; float a = 0.f;
        for (int i = 0; i < CPB; i++) {
            int cc = batch*CPB + i;
            kpre[cc*128 + d] = a;
            a += ksum[cc*128 + d];
        }
    }
}

// Phase C1: LI = Q̃ @ KVpre; PM = g * (Q̃@M) / (Q̃·z + eps); dloc = Q̃·kpre
__global__ __launch_bounds__(256) void k_attn_c1(
    const unsigned short* __restrict__ Qb, const float* __restrict__ KVpre,
    const float* __restrict__ kpre, const unsigned short* __restrict__ Mb,
    const float* __restrict__ z, const float* __restrict__ gate,
    float* __restrict__ LI, float* __restrict__ PM, float* __restrict__ dloc)
{
    __shared__ unsigned short b0[128*128];
    __shared__ unsigned short b1[128*128];
    __shared__ float dmem[128], dl[128];
    const int tid = threadIdx.x;
    const int c = blockIdx.x, t0 = c*128;
    const int wave = tid >> 6, lane = tid & 63;
    const int wm = wave >> 1, wn = wave & 1, quad = lane >> 4, lr = lane & 15;

    stage_direct(b0, Qb + (size_t)t0*Dsz, Dsz, tid);    // Q̃ (A-operand)
    // b1 <- KVpre^T (B-operand: B[k=d][n=e] = KVpre[d][e]), fp32 src -> bf16
    #pragma unroll
    for (int i = 0; i < 16; i++) {
        int s = tid + i*256; int d = s >> 5, e0 = (s & 31)*4;
        float4 v = *(const float4*)(KVpre + (size_t)c*16384 + (size_t)d*128 + e0);
        const float* vf = (const float*)&v;
        #pragma unroll
        for (int j = 0; j < 4; j++)
            b1[(size_t)((d>>3)*128 + e0 + j)*8 + (d&7)] = f2b(vf[j]);
    }
    __syncthreads();

    f32x4 accI[4][4]; zacc(accI);
    mm128(b0, b1, accI, wm, wn, quad, lr);              // inter-chunk numerator

    if (tid < 128) {
        float p = 0.f;
        for (int d = 0; d < 128; d++)
            p += b2f(b0[(size_t)((d>>3)*128 + tid)*8 + (d&7)]) * z[d];
        dmem[tid] = p + EPSF;
    } else {
        int s_ = tid - 128; float p = 0.f;
        for (int d = 0; d < 128; d++)
            p += b2f(b0[(size_t)((d>>3)*128 + s_)*8 + (d&7)]) * kpre[c*128 + d];
        dl[s_] = p;
    }
    __syncthreads();

    stage_T(b1, Mb, Dsz, tid);                          // M^T (B-operand)
    __syncthreads();

    f32x4 accM[4][4]; zacc(accM);
    mm128(b0, b1, accM, wm, wn, quad, lr);              // mem_num

    float g = 1.f / (1.f + expf(-gate[0]));
    #pragma unroll
    for (int mb = 0; mb < 4; mb++)
        #pragma unroll
        for (int nb = 0; nb < 4; nb++)
            #pragma unroll
            for (int rg = 0; rg < 4; rg++) {
                int s_ = wm*64 + mb*16 + quad*4 + rg;
                int e_ = wn*64 + nb*16 + lr;
                size_t o = (size_t)(t0 + s_)*Dsz + e_;
                LI[o] = accI[mb][nb][rg];
                PM[o] = g * accM[mb][nb][rg] / dmem[s_];
            }
    if (tid < 128) dloc[t0 + tid] = dl[tid];
}

// Phase C2: S = tril(Q̃K̃^T); P = PM + (1-g)*(LI + S@V) / (dloc + rowsum(S) + eps), bf16
__global__ __launch_bounds__(256) void k_attn_c2(
    const unsigned short* __restrict__ Qb, const unsigned short* __restrict__ Kb,
    const unsigned short* __restrict__ Vb, const float* __restrict__ LI,
    const float* __restrict__ PM, const float* __restrict__ dloc,
    const float* __restrict__ gate, unsigned short* __restrict__ P)
{
    __shared__ unsigned short b0[128*128];
    __shared__ unsigned short b1[128*128];
    __shared__ float rs[128];
    const int tid = threadIdx.x;
    const int c = blockIdx.x, t0 = c*128;
    const int wave = tid >> 6, lane = tid & 63;
    const int wm = wave >> 1, wn = wave & 1, quad = lane >> 4, lr = lane & 15;

    if (tid < 128) rs[tid] = 0.f;
    stage_direct(b0, Qb + (size_t)t0*Dsz, Dsz, tid);    // Q̃ (A-operand)
    stage_direct(b1, Kb + (size_t)t0*Dsz, Dsz, tid);    // K̃ (B-operand: B[k=d][n=t]=K̃[t,d])
    __syncthreads();

    f32x4 accS[4][4]; zacc(accS);
    mm128(b0, b1, accS, wm, wn, quad, lr);              // S[s][t]
    __syncthreads();                                    // done reading b0/b1

    // mask, rowsum, write S -> b0 (A-operand: A[m=s][k=t])
    #pragma unroll
    for (int mb = 0; mb < 4; mb++)
        #pragma unroll
        for (int rg = 0; rg < 4; rg++) {
            int s_ = wm*64 + mb*16 + quad*4 + rg;
            float part = 0.f;
            #pragma unroll
            for (int nb = 0; nb < 4; nb++) {
                int t_ = wn*64 + nb*16 + lr;
                float v = (t_ <= s_) ? accS[mb][nb][rg] : 0.f;
                part += v;
                b0[(size_t)((t_>>3)*128 + s_)*8 + (t_&7)] = f2b(v);
            }
            #pragma unroll
            for (int m = 1; m < 16; m <<= 1) part += __shfl_xor(part, m, 64);
            if (lr == 0) atomicAdd(&rs[s_], part);
        }
    stage_T(b1, Vb + (size_t)t0*Dsz, Dsz, tid);         // V^T (B-operand)
    __syncthreads();

    f32x4 accV[4][4]; zacc(accV);
    mm128(b0, b1, accV, wm, wn, quad, lr);              // intra numerator

    float g = 1.f / (1.f + expf(-gate[0]));
    #pragma unroll
    for (int mb = 0; mb < 4; mb++)
        #pragma unroll
        for (int nb = 0; nb < 4; nb++)
            #pragma unroll
            for (int rg = 0; rg < 4; rg++) {
                int s_ = wm*64 + mb*16 + quad*4 + rg;
                int e_ = wn*64 + nb*16 + lr;
                size_t o = (size_t)(t0 + s_)*Dsz + e_;
                float num = LI[o] + accV[mb][nb][rg];
                float dd  = dloc[t0 + s_] + rs[s_] + EPSF;
                float val = PM[o] + (1.f - g) * num / dd;
                P[o] = f2b(val);
            }
}

// out = P[8192,128] @ Wo[2048,128]^T, fp32 out
__global__ __launch_bounds__(256) void k_gemm_out(
    const unsigned short* __restrict__ P, const unsigned short* __restrict__ Wo,
    float* __restrict__ out)
{
    __shared__ unsigned short b0[128*128];
    __shared__ unsigned short b1[128*128];
    const int tid = threadIdx.x;
    const int row0 = blockIdx.x*128, n0 = blockIdx.y*128;
    const int wave = tid >> 6, lane = tid & 63;
    const int wm = wave >> 1, wn = wave & 1, quad = lane >> 4, lr = lane & 15;

    stage_direct(b0, P  + (size_t)row0*Dsz, Dsz, tid);
    stage_direct(b1, Wo + (size_t)n0*Dsz,  Dsz, tid);
    __syncthreads();

    f32x4 acc[4][4]; zacc(acc);
    mm128(b0, b1, acc, wm, wn, quad, lr);
    #pragma unroll
    for (int mb = 0; mb < 4; mb++)
        #pragma unroll
        for (int nb = 0; nb < 4; nb++)
            #pragma unroll
            for (int rg = 0; rg < 4; rg++) {
                int s_ = wm*64 + mb*16 + quad*4 + rg;
                int e_ = wn*64 + nb*16 + lr;
                out[(size_t)(row0 + s_)*Hsz + n0 + e_] = acc[mb][nb][rg];
            }
}

__global__ void k_final_mz(const float* __restrict__ M, const float* __restrict__ z,
                           const float* __restrict__ Mpart, const float* __restrict__ ksum,
                           float* __restrict__ omz)
{
    int idx = blockIdx.x*256 + threadIdx.x;
    if (idx < 16384) {
        float a = M[idx];
        for (int c = 0; c < NCH; c++) a += Mpart[(size_t)c*16384 + idx];
        omz[idx] = a;
    } else if (idx < 16512) {
        int d = idx - 16384; float a = z[d];
        for (int c = 0; c < NCH; c++) a += ksum[c*128 + d];
        omz[16384 + d] = a;
    }
}

// ---------------- launcher ----------------
extern "C" void kernel_launch(void* const* d_in, const int* in_sizes, int n_in,
                              void* d_out, int out_size, void* d_ws, size_t ws_size,
                              hipStream_t stream)
{
    const float* X    = (const float*)d_in[0];
    const float* wq   = (const float*)d_in[1];
    const float* wk   = (const float*)d_in[2];
    const float* wv   = (const float*)d_in[3];
    const float* wo   = (const float*)d_in[4];
    const float* gate = (const float*)d_in[5];
    const float* M    = (const float*)d_in[6];
    const float* z    = (const float*)d_in[7];

    char* ws = (char*)d_ws;
    unsigned short* Wqkv = (unsigned short*)(ws + WQKV_OFF);
    unsigned short* Wo_b = (unsigned short*)(ws + WO_OFF);
    unsigned short* Mb   = (unsigned short*)(ws + MB_OFF);
    unsigned short* Qb   = (unsigned short*)(ws + QB_OFF);
    unsigned short* Kb   = (unsigned short*)(ws + KB_OFF);
    unsigned short* Vb   = (unsigned short*)(ws + VB_OFF);
    unsigned short* Pb   = (unsigned short*)(ws + P_OFF);
    float* KV    = (float*)(ws + KV_OFF);
    float* KVpre = (float*)(ws + KVPRE_OFF);
    float* ksum  = (float*)(ws + KSUM_OFF);
    float* kpre  = (float*)(ws + KPRE_OFF);
    float* Mpart = (float*)(ws + MPART_OFF);
    float* LI    = (float*)(ws + LI_OFF);
    float* PM    = (float*)(ws + PM_OFF);
    float* dloc  = (float*)(ws + DLOC_OFF);

    float* outp   = (float*)d_out;
    float* out_mz = outp + (size_t)Nrow*Hsz;

    const int WN = Dsz * Hsz;   // 262144 per weight matrix
    k_cvt<<<(WN+255)/256, 256, 0, stream>>>(wq, Wqkv,            WN);
    k_cvt<<<(WN+255)/256, 256, 0, stream>>>(wk, Wqkv + WN,       WN);
    k_cvt<<<(WN+255)/256, 256, 0, stream>>>(wv, Wqkv + 2*WN,     WN);
    k_cvt<<<(WN+255)/256, 256, 0, stream>>>(wo, Wo_b,            WN);
    k_cvt<<<(16384+255)/256, 256, 0, stream>>>(M, Mb,            16384);

    k_gemm_qkv<<<dim3(Nrow/128, 3), 256, 0, stream>>>(X, Wqkv, Qb, Kb, Vb);
    k_delta_kv<<<NCH, 256, 0, stream>>>(Kb, Vb, Mb, z, KV, ksum, Mpart);
    k_prefix<<<(2*16512 + 255)/256, 256, 0, stream>>>(KV, ksum, KVpre, kpre);
    k_attn_c1<<<NCH, 256, 0, stream>>>(Qb, KVpre, kpre, Mb, z, gate, LI, PM, dloc);
    k_attn_c2<<<NCH, 256, 0, stream>>>(Qb, Kb, Vb, LI, PM, dloc, gate, Pb);
    k_gemm_out<<<dim3(Nrow/128, Hsz/128), 256, 0, stream>>>(Pb, Wo_b, outp);
    k_final_mz<<<(16512 + 255)/256, 256, 0, stream>>>(M, z, Mpart, ksum, out_mz);
}

// Round 2
// 232.388 us; speedup vs baseline: 1.1999x; 1.1999x over previous
//
#include <hip/hip_runtime.h>
#include <hip/hip_bf16.h>
#include <math.h>

#define DI __device__ __forceinline__

typedef __bf16 bf16x8 __attribute__((ext_vector_type(8)));
typedef float  f32x4  __attribute__((ext_vector_type(4)));

static constexpr int   Bsz  = 2, Ssz = 4096, Hsz = 2048, Dsz = 128;
static constexpr int   Nrow = Bsz * Ssz;     // 8192
static constexpr int   NCH  = Nrow / 128;    // 64 chunks
static constexpr int   CPB  = Ssz / 128;     // 32 chunks per batch
static constexpr int   WN   = Dsz * Hsz;     // 262144
static constexpr float EPSF = 1e-6f;

// ---------------- workspace layout (bytes) ----------------
static constexpr size_t WQKV_OFF = 0;                            // bf16 [384][2048]
static constexpr size_t WO_OFF   = (size_t)3*WN*2;               // bf16 [2048][128]
static constexpr size_t MB_OFF   = WO_OFF + (size_t)WN*2;        // bf16 [128][128]
static constexpr size_t MBT_OFF  = MB_OFF + 32768;               // bf16 M^T [128][128]
static constexpr size_t QB_OFF   = MBT_OFF + 32768;              // bf16 [8192][128]
static constexpr size_t KB_OFF   = QB_OFF + (size_t)Nrow*Dsz*2;
static constexpr size_t VB_OFF   = KB_OFF + (size_t)Nrow*Dsz*2;
static constexpr size_t PB_OFF   = VB_OFF + (size_t)Nrow*Dsz*2;
static constexpr size_t ACC_OFF  = PB_OFF + (size_t)Nrow*Dsz*2;  // f32 [3][8192][128] = 12.58MB
// --- aliased into ACC region (dead after k_qkv_epi) ---
static constexpr size_t KVT_OFF  = ACC_OFF;                      // f32 [64][128e][128d]
static constexpr size_t KVTP_OFF = ACC_OFF + (size_t)4*1024*1024;// bf16 [64][128e][128d]
static constexpr size_t MPART_OFF= ACC_OFF + (size_t)6*1024*1024;// f32 [64][128][128]
static constexpr size_t KSUM_OFF = ACC_OFF + (size_t)10*1024*1024;// f32 [64][128]
static constexpr size_t KPRE_OFF = KSUM_OFF + 32768;             // f32 [64][128]

// ---------------- helpers ----------------
DI float b2f(unsigned short u) {
    union { float f; unsigned int i; } x; x.i = ((unsigned int)u) << 16; return x.f;
}
DI unsigned short f2b(float f) {
    __bf16 h = (__bf16)f; return __builtin_bit_cast(unsigned short, h);
}
DI float sig_elu(float x) { return x > 0.f ? x + 1.f : expf(x); }

DI f32x4 MFMA(bf16x8 a, bf16x8 b, f32x4 c) {
    return __builtin_amdgcn_mfma_f32_16x16x32_bf16(a, b, c, 0, 0, 0);
}
DI void zacc(f32x4 (&acc)[4][4]) {
    f32x4 zz = {0.f, 0.f, 0.f, 0.f};
    #pragma unroll
    for (int i = 0; i < 4; i++)
        #pragma unroll
        for (int j = 0; j < 4; j++) acc[i][j] = zz;
}

// swizzled chunk offset (in ushorts) of 8-elem chunk (r, kc):
// banks spread by XOR-ing kc into the low bits of r
DI int swz(int r, int kc) { return (kc*128 + (r ^ (kc & 7))) * 8; }
// element (r,k) lives at swz(r, k>>3) + (k&7)

template<int NKS>
DI void mm_steps(const unsigned short* A, const unsigned short* Bm, f32x4 (&acc)[4][4],
                 int wm, int wn, int quad, int lr) {
    #pragma unroll
    for (int ks = 0; ks < NKS; ks++) {
        bf16x8 a[4], b[4];
        #pragma unroll
        for (int mb = 0; mb < 4; mb++)
            a[mb] = *(const bf16x8*)&A[swz(wm*64 + mb*16 + lr, ks*4 + quad)];
        #pragma unroll
        for (int nb = 0; nb < 4; nb++)
            b[nb] = *(const bf16x8*)&Bm[swz(wn*64 + nb*16 + lr, ks*4 + quad)];
        #pragma unroll
        for (int mb = 0; mb < 4; mb++)
            #pragma unroll
            for (int nb = 0; nb < 4; nb++)
                acc[mb][nb] = MFMA(a[mb], b[nb], acc[mb][nb]);
    }
}

// row-major [128][128] bf16 tile -> operand layout (coalesced global, 2-way LDS writes)
DI void stage_direct(unsigned short* dst, const unsigned short* src, int src_ld, int tid) {
    #pragma unroll
    for (int i = 0; i < 8; i++) {
        int s = tid + i*256; int r = s >> 4, kc = s & 15;
        *(uint4*)&dst[swz(r, kc)] = *(const uint4*)(src + (size_t)r*src_ld + kc*8);
    }
}

// transposed staging: operand elem (r=col, k=row) <- src[row][col]
// lane mapping chosen for LDS banking (8-way) over global coalescing (L2-hot sources)
DI void stage_T(unsigned short* dst, const unsigned short* src, int src_ld, int tid) {
    #pragma unroll
    for (int i = 0; i < 8; i++) {
        int s = tid + i*256;
        int rw = (s & 15) + ((s >> 8) << 4);
        int c0 = ((s >> 4) & 15) * 8;
        unsigned short tmp[8];
        *(uint4*)tmp = *(const uint4*)(src + (size_t)rw*src_ld + c0);
        #pragma unroll
        for (int j = 0; j < 8; j++)
            dst[swz(c0 + j, rw >> 3) + (rw & 7)] = tmp[j];
    }
}

// ---------------- kernels ----------------

// fused weight conversion: wq|wk|wv -> Wqkv, wo -> Wo, M -> Mb and MbT
__global__ void k_cvt_w(const float* __restrict__ wq, const float* __restrict__ wk,
                        const float* __restrict__ wv, const float* __restrict__ wo,
                        const float* __restrict__ M, unsigned short* __restrict__ dst,
                        unsigned short* __restrict__ MbT)
{
    int gid = blockIdx.x*256 + threadIdx.x;
    if (gid >= (4*WN + 16384)/4) return;
    int e = gid*4;
    const float* src; int rel;
    if      (e < WN)     { src = wq; rel = e; }
    else if (e < 2*WN)   { src = wk; rel = e - WN; }
    else if (e < 3*WN)   { src = wv; rel = e - 2*WN; }
    else if (e < 4*WN)   { src = wo; rel = e - 3*WN; }
    else                 { src = M;  rel = e - 4*WN; }
    float4 v = *(const float4*)(src + rel);
    const float* vf = (const float*)&v;
    unsigned short o[4];
    #pragma unroll
    for (int j = 0; j < 4; j++) o[j] = f2b(vf[j]);
    *(uint2*)&dst[e] = *(const uint2*)o;
    if (e >= 4*WN) {
        #pragma unroll
        for (int j = 0; j < 4; j++) {
            int d = (rel + j) >> 7, ee = (rel + j) & 127;
            MbT[ee*128 + d] = o[j];
        }
    }
}

// QKV projection, split-K=4: X[8192,2048]fp32 @ Wqkv[384,2048]^T, atomic fp32 accumulate
__global__ __launch_bounds__(256, 3) void k_gemm_qkv(
    const float* __restrict__ X, const unsigned short* __restrict__ W,
    float* __restrict__ Acc)
{
    __shared__ unsigned short lA[128*64];
    __shared__ unsigned short lB[128*64];
    const int tid = threadIdx.x;
    const int row0 = blockIdx.x * 128;
    const int ct   = blockIdx.y;
    const int n0   = ct * 128;
    const int kb   = blockIdx.z * 512;
    const int wave = tid >> 6, lane = tid & 63;
    const int wm = wave >> 1, wn = wave & 1;
    const int quad = lane >> 4, lr = lane & 15;

    f32x4 acc[4][4]; zacc(acc);

    for (int kt = kb; kt < kb + 512; kt += 64) {
        #pragma unroll
        for (int i = 0; i < 4; i++) {            // A: fp32 -> bf16 inline
            int s = tid + i*256; int r = s >> 3, kc = s & 7;
            const float* gp = X + (size_t)(row0 + r)*Hsz + kt + kc*8;
            float4 a0 = *(const float4*)gp;
            float4 a1 = *(const float4*)(gp + 4);
            const float* f0 = (const float*)&a0;
            const float* f1 = (const float*)&a1;
            unsigned short tmp[8];
            #pragma unroll
            for (int j = 0; j < 4; j++) { tmp[j] = f2b(f0[j]); tmp[4+j] = f2b(f1[j]); }
            *(uint4*)&lA[swz(r, kc)] = *(const uint4*)tmp;
        }
        #pragma unroll
        for (int i = 0; i < 4; i++) {            // B: bf16 16B copy
            int s = tid + i*256; int r = s >> 3, kc = s & 7;
            *(uint4*)&lB[swz(r, kc)] = *(const uint4*)(W + (size_t)(n0 + r)*Hsz + kt + kc*8);
        }
        __syncthreads();
        mm_steps<2>(lA, lB, acc, wm, wn, quad, lr);
        __syncthreads();
    }

    float* base = Acc + (size_t)ct*Nrow*128;
    #pragma unroll
    for (int mb = 0; mb < 4; mb++)
        #pragma unroll
        for (int nb = 0; nb < 4; nb++)
            #pragma unroll
            for (int rg = 0; rg < 4; rg++) {
                int s_ = wm*64 + mb*16 + quad*4 + rg;
                int e_ = wn*64 + nb*16 + lr;
                atomicAdd(&base[(size_t)(row0 + s_)*128 + e_], acc[mb][nb][rg]);
            }
}

// epilogue: sum'd accumulator -> sigma (q,k) -> bf16 Q/K/V
__global__ void k_qkv_epi(const float* __restrict__ Acc, unsigned short* __restrict__ Qb,
                          unsigned short* __restrict__ Kb, unsigned short* __restrict__ Vb)
{
    int gid = blockIdx.x*256 + threadIdx.x;         // 786432 threads
    int ct = gid / (Nrow*32);
    int off = (gid - ct*Nrow*32) * 4;
    float4 v = *(const float4*)(Acc + (size_t)ct*Nrow*128 + off);
    const float* vf = (const float*)&v;
    unsigned short* dst = (ct == 0) ? Qb : (ct == 1 ? Kb : Vb);
    unsigned short o[4];
    if (ct < 2) {
        #pragma unroll
        for (int j = 0; j < 4; j++) o[j] = f2b(sig_elu(vf[j]));
    } else {
        #pragma unroll
        for (int j = 0; j < 4; j++) o[j] = f2b(vf[j]);
    }
    *(uint2*)&dst[off] = *(const uint2*)o;
}

// per chunk: vret=(K̃M)/(K̃·z+eps); Mpart=K̃^T(V-vret); KVT=V^T K̃; ksum=colsum K̃
__global__ __launch_bounds__(256, 1) void k_delta_kv(
    const unsigned short* __restrict__ Kb, const unsigned short* __restrict__ Vb,
    const unsigned short* __restrict__ MbT, const float* __restrict__ z,
    float* __restrict__ KVT, float* __restrict__ ksum, float* __restrict__ Mpart)
{
    __shared__ unsigned short b0[128*128];
    __shared__ unsigned short b1[128*128];
    __shared__ float den[128];
    const int tid = threadIdx.x;
    const int c = blockIdx.x, t0 = c*128;
    const int wave = tid >> 6, lane = tid & 63;
    const int wm = wave >> 1, wn = wave & 1, quad = lane >> 4, lr = lane & 15;

    stage_direct(b0, Kb + (size_t)t0*Dsz, Dsz, tid);   // K̃  (A)
    stage_direct(b1, MbT, Dsz, tid);                    // M^T (B: B[k=d][n=e]=M[d][e])
    __syncthreads();

    f32x4 acc1[4][4]; zacc(acc1);
    mm_steps<4>(b0, b1, acc1, wm, wn, quad, lr);        // vret_num[t][e]

    if (tid < 128) {
        float p = 0.f;
        for (int d = 0; d < 128; d++)
            p += b2f(b0[swz(tid, d >> 3) + (d & 7)]) * z[d];
        den[tid] = p + EPSF;
    }
    __syncthreads();

    stage_T(b1, Kb + (size_t)t0*Dsz, Dsz, tid);         // K̃^T: elem (d,t)=K̃[t][d]
    #pragma unroll
    for (int mb = 0; mb < 4; mb++)                       // b0 <- W = V - vret (B: elem (e,t))
        #pragma unroll
        for (int nb = 0; nb < 4; nb++)
            #pragma unroll
            for (int rg = 0; rg < 4; rg++) {
                int s_ = wm*64 + mb*16 + quad*4 + rg;
                int e_ = wn*64 + nb*16 + lr;
                float v = b2f(Vb[(size_t)(t0 + s_)*Dsz + e_]);
                float w = v - acc1[mb][nb][rg] / den[s_];
                b0[swz(e_, s_ >> 3) + (s_ & 7)] = f2b(w);
            }
    __syncthreads();

    if (tid < 128) {
        float p = 0.f;
        for (int t = 0; t < 128; t++)
            p += b2f(b1[swz(tid, t >> 3) + (t & 7)]);
        ksum[(size_t)c*128 + tid] = p;
    }
    f32x4 acc2[4][4]; zacc(acc2);
    mm_steps<4>(b1, b0, acc2, wm, wn, quad, lr);        // Mpart[d][e]
    #pragma unroll
    for (int mb = 0; mb < 4; mb++)
        #pragma unroll
        for (int nb = 0; nb < 4; nb++)
            #pragma unroll
            for (int rg = 0; rg < 4; rg++) {
                int d_ = wm*64 + mb*16 + quad*4 + rg;
                int e_ = wn*64 + nb*16 + lr;
                Mpart[(size_t)c*16384 + (size_t)d_*128 + e_] = acc2[mb][nb][rg];
            }
    __syncthreads();

    stage_T(b0, Vb + (size_t)t0*Dsz, Dsz, tid);         // V^T (A: elem (e,t)=V[t][e])
    __syncthreads();

    f32x4 acc3[4][4]; zacc(acc3);
    mm_steps<4>(b0, b1, acc3, wm, wn, quad, lr);        // KVT[e][d] = sum_t V[t][e]K̃[t][d]
    #pragma unroll
    for (int mb = 0; mb < 4; mb++)
        #pragma unroll
        for (int nb = 0; nb < 4; nb++)
            #pragma unroll
            for (int rg = 0; rg < 4; rg++) {
                int e_ = wm*64 + mb*16 + quad*4 + rg;
                int d_ = wn*64 + nb*16 + lr;
                KVT[(size_t)c*16384 + (size_t)e_*128 + d_] = acc3[mb][nb][rg];
            }
}

// fused: exclusive chunk-prefix of KVT (-> bf16) and ksum, plus final M_new / z_new
__global__ void k_scan_final(
    const float* __restrict__ KVT, const float* __restrict__ ksum,
    const float* __restrict__ M, const float* __restrict__ z,
    const float* __restrict__ Mpart, unsigned short* __restrict__ KVTp,
    float* __restrict__ kpre, float* __restrict__ omz)
{
    int idx = blockIdx.x*256 + threadIdx.x;
    if (idx < 32768) {                       // KVT scan (per batch)
        int batch = idx >> 14, ed = idx & 16383;
        float a = 0.f;
        #pragma unroll 8
        for (int i = 0; i < CPB; i++) {
            size_t cc = (size_t)(batch*CPB + i);
            KVTp[cc*16384 + ed] = f2b(a);
            a += KVT[cc*16384 + ed];
        }
    } else if (idx < 33024) {                // ksum scan
        int j = idx - 32768; int batch = j >> 7, d = j & 127;
        float a = 0.f;
        #pragma unroll 8
        for (int i = 0; i < CPB; i++) {
            int cc = batch*CPB + i;
            kpre[cc*128 + d] = a;
            a += ksum[cc*128 + d];
        }
    } else if (idx < 49408) {                // M_new
        int m = idx - 33024;
        float a = M[m];
        #pragma unroll 8
        for (int cc = 0; cc < NCH; cc++) a += Mpart[(size_t)cc*16384 + m];
        omz[m] = a;
    } else if (idx < 49536) {                // z_new
        int d = idx - 49408;
        float a = z[d];
        #pragma unroll 8
        for (int cc = 0; cc < NCH; cc++) a += ksum[cc*128 + d];
        omz[16384 + d] = a;
    }
}

// fused attention: memory-retrieve + inter-chunk + intra-chunk causal, -> P bf16
__global__ __launch_bounds__(256, 1) void k_attn(
    const unsigned short* __restrict__ Qb, const unsigned short* __restrict__ KVTp,
    const float* __restrict__ kpre, const unsigned short* __restrict__ MbT,
    const float* __restrict__ z, const float* __restrict__ gate,
    const unsigned short* __restrict__ Kb, const unsigned short* __restrict__ Vb,
    unsigned short* __restrict__ P)
{
    __shared__ unsigned short b0[128*128];
    __shared__ unsigned short b1[128*128];
    __shared__ float dmem[128], dl[128], rs[128];
    const int tid = threadIdx.x;
    const int c = blockIdx.x, t0 = c*128;
    const int wave = tid >> 6, lane = tid & 63;
    const int wm = wave >> 1, wn = wave & 1, quad = lane >> 4, lr = lane & 15;

    if (tid < 128) rs[tid] = 0.f;
    stage_direct(b0, Qb + (size_t)t0*Dsz, Dsz, tid);    // Q̃ (A)
    stage_direct(b1, MbT, Dsz, tid);                     // M^T (B)
    __syncthreads();                                     // #1

    if (tid < 128) {                                     // dmem = Q̃·z + eps
        float p = 0.f;
        for (int d = 0; d < 128; d++)
            p += b2f(b0[swz(tid, d >> 3) + (d & 7)]) * z[d];
        dmem[tid] = p + EPSF;
    } else {                                             // dl = Q̃·kpre
        int s_ = tid - 128; float p = 0.f;
        for (int d = 0; d < 128; d++)
            p += b2f(b0[swz(s_, d >> 3) + (d & 7)]) * kpre[c*128 + d];
        dl[s_] = p;
    }
    f32x4 accM[4][4]; zacc(accM);
    mm_steps<4>(b0, b1, accM, wm, wn, quad, lr);         // mem_num[t][e]
    __syncthreads();                                     // #2

    stage_direct(b1, KVTp + (size_t)c*16384, Dsz, tid);  // KVpre (B: elem (e,d)=KVT[e][d])
    float g = 1.f / (1.f + expf(-gate[0]));
    f32x4 base[4][4];
    #pragma unroll
    for (int mb = 0; mb < 4; mb++)
        #pragma unroll
        for (int nb = 0; nb < 4; nb++)
            #pragma unroll
            for (int rg = 0; rg < 4; rg++) {
                int s_ = wm*64 + mb*16 + quad*4 + rg;
                base[mb][nb][rg] = g * accM[mb][nb][rg] / dmem[s_];
            }
    __syncthreads();                                     // #3

    f32x4 accN[4][4]; zacc(accN);
    mm_steps<4>(b0, b1, accN, wm, wn, quad, lr);         // inter numerator
    __syncthreads();                                     // #4

    stage_direct(b1, Kb + (size_t)t0*Dsz, Dsz, tid);     // K̃ (B: S=Q̃K̃^T)
    __syncthreads();                                     // #5

    f32x4 accS[4][4]; zacc(accS);
    mm_steps<4>(b0, b1, accS, wm, wn, quad, lr);         // S[t][t2]
    __syncthreads();                                     // #6

    #pragma unroll
    for (int mb = 0; mb < 4; mb++)                       // mask + rowsum + S -> b0 (A)
        #pragma unroll
        for (int rg = 0; rg < 4; rg++) {
            int s_ = wm*64 + mb*16 + quad*4 + rg;
            float part = 0.f;
            #pragma unroll
            for (int nb = 0; nb < 4; nb++) {
                int t_ = wn*64 + nb*16 + lr;
                float v = (t_ <= s_) ? accS[mb][nb][rg] : 0.f;
                part += v;
                b0[swz(s_, t_ >> 3) + (t_ & 7)] = f2b(v);
            }
            #pragma unroll
            for (int m = 1; m < 16; m <<= 1) part += __shfl_xor(part, m, 64);
            if (lr == 0) atomicAdd(&rs[s_], part);
        }
    stage_T(b1, Vb + (size_t)t0*Dsz, Dsz, tid);          // V^T (B)
    __syncthreads();                                     // #7

    f32x4 accV[4][4]; zacc(accV);
    mm_steps<4>(b0, b1, accV, wm, wn, quad, lr);         // intra numerator

    #pragma unroll
    for (int mb = 0; mb < 4; mb++)
        #pragma unroll
        for (int nb = 0; nb < 4; nb++)
            #pragma unroll
            for (int rg = 0; rg < 4; rg++) {
                int s_ = wm*64 + mb*16 + quad*4 + rg;
                int e_ = wn*64 + nb*16 + lr;
                float num = accN[mb][nb][rg] + accV[mb][nb][rg];
                float dd  = dl[s_] + rs[s_] + EPSF;
                float val = base[mb][nb][rg] + (1.f - g) * num / dd;
                P[(size_t)(t0 + s_)*Dsz + e_] = f2b(val);
            }
}

// out = P[8192,128] @ Wo[2048,128]^T, fp32
__global__ __launch_bounds__(256, 2) void k_gemm_out(
    const unsigned short* __restrict__ P, const unsigned short* __restrict__ Wo,
    float* __restrict__ out)
{
    __shared__ unsigned short b0[128*128];
    __shared__ unsigned short b1[128*128];
    const int tid = threadIdx.x;
    const int row0 = blockIdx.x*128, n0 = blockIdx.y*128;
    const int wave = tid >> 6, lane = tid & 63;
    const int wm = wave >> 1, wn = wave & 1, quad = lane >> 4, lr = lane & 15;

    stage_direct(b0, P  + (size_t)row0*Dsz, Dsz, tid);
    stage_direct(b1, Wo + (size_t)n0*Dsz,  Dsz, tid);
    __syncthreads();

    f32x4 acc[4][4]; zacc(acc);
    mm_steps<4>(b0, b1, acc, wm, wn, quad, lr);
    #pragma unroll
    for (int mb = 0; mb < 4; mb++)
        #pragma unroll
        for (int nb = 0; nb < 4; nb++)
            #pragma unroll
            for (int rg = 0; rg < 4; rg++) {
                int s_ = wm*64 + mb*16 + quad*4 + rg;
                int e_ = wn*64 + nb*16 + lr;
                out[(size_t)(row0 + s_)*Hsz + n0 + e_] = acc[mb][nb][rg];
            }
}

// ---------------- launcher ----------------
extern "C" void kernel_launch(void* const* d_in, const int* in_sizes, int n_in,
                              void* d_out, int out_size, void* d_ws, size_t ws_size,
                              hipStream_t stream)
{
    const float* X    = (const float*)d_in[0];
    const float* wq   = (const float*)d_in[1];
    const float* wk   = (const float*)d_in[2];
    const float* wv   = (const float*)d_in[3];
    const float* wo   = (const float*)d_in[4];
    const float* gate = (const float*)d_in[5];
    const float* M    = (const float*)d_in[6];
    const float* z    = (const float*)d_in[7];

    char* ws = (char*)d_ws;
    unsigned short* Wfull = (unsigned short*)(ws + WQKV_OFF);   // Wqkv|Wo|Mb contiguous
    unsigned short* Wo_b  = (unsigned short*)(ws + WO_OFF);
    unsigned short* MbT   = (unsigned short*)(ws + MBT_OFF);
    unsigned short* Qb    = (unsigned short*)(ws + QB_OFF);
    unsigned short* Kb    = (unsigned short*)(ws + KB_OFF);
    unsigned short* Vb    = (unsigned short*)(ws + VB_OFF);
    unsigned short* Pb    = (unsigned short*)(ws + PB_OFF);
    float* Acc   = (float*)(ws + ACC_OFF);
    float* KVT   = (float*)(ws + KVT_OFF);
    unsigned short* KVTp = (unsigned short*)(ws + KVTP_OFF);
    float* Mpart = (float*)(ws + MPART_OFF);
    float* ksum  = (float*)(ws + KSUM_OFF);
    float* kpre  = (float*)(ws + KPRE_OFF);

    float* outp   = (float*)d_out;
    float* out_mz = outp + (size_t)Nrow*Hsz;

    k_cvt_w<<<((4*WN + 16384)/4 + 255)/256, 256, 0, stream>>>(wq, wk, wv, wo, M, Wfull, MbT);
    hipMemsetAsync(Acc, 0, (size_t)3*Nrow*128*4, stream);
    k_gemm_qkv<<<dim3(Nrow/128, 3, 4), 256, 0, stream>>>(X, Wfull, Acc);
    k_qkv_epi<<<(3*Nrow*128/4)/256, 256, 0, stream>>>(Acc, Qb, Kb, Vb);
    k_delta_kv<<<NCH, 256, 0, stream>>>(Kb, Vb, MbT, z, KVT, ksum, Mpart);
    k_scan_final<<<194, 256, 0, stream>>>(KVT, ksum, M, z, Mpart, KVTp, kpre, out_mz);
    k_attn<<<NCH, 256, 0, stream>>>(Qb, KVTp, kpre, MbT, z, gate, Kb, Vb, Pb);
    k_gemm_out<<<dim3(Nrow/128, Hsz/128), 256, 0, stream>>>(Pb, Wo_b, outp);
}

// Round 3
// 207.832 us; speedup vs baseline: 1.3416x; 1.1182x over previous
//
#include <hip/hip_runtime.h>
#include <hip/hip_bf16.h>
#include <math.h>

#define DI __device__ __forceinline__

typedef __bf16 bf16x8 __attribute__((ext_vector_type(8)));
typedef float  f32x4  __attribute__((ext_vector_type(4)));

static constexpr int   Bsz  = 2, Ssz = 4096, Hsz = 2048, Dsz = 128;
static constexpr int   Nrow = Bsz * Ssz;     // 8192
static constexpr int   NCH  = Nrow / 128;    // 64 chunks
static constexpr int   CPB  = Ssz / 128;     // 32 chunks per batch
static constexpr int   WN   = Dsz * Hsz;     // 262144
static constexpr float EPSF = 1e-6f;

// ---------------- workspace layout (bytes) ----------------
static constexpr size_t WQKV_OFF = 0;                            // bf16 [384][2048]
static constexpr size_t WO_OFF   = (size_t)3*WN*2;               // bf16 [2048][128]
static constexpr size_t MB_OFF   = WO_OFF + (size_t)WN*2;        // bf16 [128][128] (cvt spill)
static constexpr size_t MBT_OFF  = MB_OFF + 32768;               // bf16 M^T [128][128]
static constexpr size_t QB_OFF   = MBT_OFF + 32768;              // bf16 [8192][128]
static constexpr size_t KB_OFF   = QB_OFF + (size_t)Nrow*Dsz*2;
static constexpr size_t VB_OFF   = KB_OFF + (size_t)Nrow*Dsz*2;
static constexpr size_t PB_OFF   = VB_OFF + (size_t)Nrow*Dsz*2;
static constexpr size_t ACC_OFF  = PB_OFF + (size_t)Nrow*Dsz*2;  // bf16 [4][3][8192][128] = 25.2MB
// --- aliased into ACC region (dead after k_qkv_epi) ---
static constexpr size_t KVT_OFF  = ACC_OFF;                      // f32 [64][128e][128d] 4MB
static constexpr size_t KVTP_OFF = ACC_OFF + (size_t)4*1024*1024;// bf16 [64][128e][128d] 2MB
static constexpr size_t MPART_OFF= ACC_OFF + (size_t)6*1024*1024;// f32 [64][128][128] 4MB
static constexpr size_t KSUM_OFF = ACC_OFF + (size_t)10*1024*1024;// f32 [64][128]
static constexpr size_t KPRE_OFF = KSUM_OFF + 32768;             // f32 [64][128]

// ---------------- helpers ----------------
DI float b2f(unsigned short u) {
    union { float f; unsigned int i; } x; x.i = ((unsigned int)u) << 16; return x.f;
}
DI unsigned short f2b(float f) {
    __bf16 h = (__bf16)f; return __builtin_bit_cast(unsigned short, h);
}
DI float sig_elu(float x) { return x > 0.f ? x + 1.f : expf(x); }

DI f32x4 MFMA(bf16x8 a, bf16x8 b, f32x4 c) {
    return __builtin_amdgcn_mfma_f32_16x16x32_bf16(a, b, c, 0, 0, 0);
}
template<int NB>
DI void zaccg(f32x4 (&acc)[4][NB]) {
    f32x4 zz = {0.f, 0.f, 0.f, 0.f};
    #pragma unroll
    for (int i = 0; i < 4; i++)
        #pragma unroll
        for (int j = 0; j < NB; j++) acc[i][j] = zz;
}

// swizzled chunk offset (ushorts) of 8-elem chunk (r, kc) in an operand tile
// with R rows: banks spread by XOR-ing kc into low bits of r
DI int swzR(int r, int kc, int R) { return (kc*R + (r ^ (kc & 7))) * 8; }
// element (r,k) lives at swzR(r, k>>3, R) + (k&7)

// generic matmul: A is 128-row operand, B is (NB*32)-row operand, output
// per-wave 4 x NB tiles of 16x16; NKS k-steps of 32.
template<int NKS, int NB>
DI void mmg(const unsigned short* A, const unsigned short* Bm, f32x4 (&acc)[4][NB],
            int wm, int wn, int quad, int lr) {
    #pragma unroll
    for (int ks = 0; ks < NKS; ks++) {
        bf16x8 a[4], b[NB];
        #pragma unroll
        for (int mb = 0; mb < 4; mb++)
            a[mb] = *(const bf16x8*)&A[swzR(wm*64 + mb*16 + lr, ks*4 + quad, 128)];
        #pragma unroll
        for (int nb = 0; nb < NB; nb++)
            b[nb] = *(const bf16x8*)&Bm[swzR(wn*(NB*16) + nb*16 + lr, ks*4 + quad, NB*32)];
        #pragma unroll
        for (int mb = 0; mb < 4; mb++)
            #pragma unroll
            for (int nb = 0; nb < NB; nb++)
                acc[mb][nb] = MFMA(a[mb], b[nb], acc[mb][nb]);
    }
}

// row-major [R][128] bf16 tile -> operand layout
template<int R>
DI void stage_dir(unsigned short* dst, const unsigned short* src, int src_ld, int tid) {
    #pragma unroll
    for (int i = 0; i < R/16; i++) {
        int s = tid + i*256; int r = s >> 4, kc = s & 15;
        *(uint4*)&dst[swzR(r, kc, R)] = *(const uint4*)(src + (size_t)r*src_ld + kc*8);
    }
}

// transposed staging (full): operand elem (r=col, k=row) <- src[row][col]
DI void stage_T128(unsigned short* dst, const unsigned short* src, int src_ld, int tid) {
    #pragma unroll
    for (int i = 0; i < 8; i++) {
        int s = tid + i*256;
        int rw = (s & 15) + ((s >> 8) << 4);
        int c0 = ((s >> 4) & 15) * 8;
        unsigned short tmp[8];
        *(uint4*)tmp = *(const uint4*)(src + (size_t)rw*src_ld + c0);
        #pragma unroll
        for (int j = 0; j < 8; j++)
            dst[swzR(c0 + j, rw >> 3, 128) + (rw & 7)] = tmp[j];
    }
}

// transposed staging into 64-row operand: elem (r=col-colOff, k=row) <- src[row][colOff+col]
DI void stage_T64(unsigned short* dst, const unsigned short* src, int src_ld, int colOff, int tid) {
    #pragma unroll
    for (int i = 0; i < 4; i++) {
        int s = tid + i*256;                     // 0..1023
        int rw = (s & 15) + ((s >> 7) << 4);     // 0..127
        int c0 = ((s >> 4) & 7) * 8;             // 0..56
        unsigned short tmp[8];
        *(uint4*)tmp = *(const uint4*)(src + (size_t)rw*src_ld + colOff + c0);
        #pragma unroll
        for (int j = 0; j < 8; j++)
            dst[swzR(c0 + j, rw >> 3, 64) + (rw & 7)] = tmp[j];
    }
}

// ---------------- kernels ----------------

// fused weight conversion: wq|wk|wv -> Wqkv, wo -> Wo, M -> (spill) and MbT
__global__ void k_cvt_w(const float* __restrict__ wq, const float* __restrict__ wk,
                        const float* __restrict__ wv, const float* __restrict__ wo,
                        const float* __restrict__ M, unsigned short* __restrict__ dst,
                        unsigned short* __restrict__ MbT)
{
    int gid = blockIdx.x*256 + threadIdx.x;
    if (gid >= (4*WN + 16384)/4) return;
    int e = gid*4;
    const float* src; int rel;
    if      (e < WN)     { src = wq; rel = e; }
    else if (e < 2*WN)   { src = wk; rel = e - WN; }
    else if (e < 3*WN)   { src = wv; rel = e - 2*WN; }
    else if (e < 4*WN)   { src = wo; rel = e - 3*WN; }
    else                 { src = M;  rel = e - 4*WN; }
    float4 v = *(const float4*)(src + rel);
    const float* vf = (const float*)&v;
    unsigned short o[4];
    #pragma unroll
    for (int j = 0; j < 4; j++) o[j] = f2b(vf[j]);
    *(uint2*)&dst[e] = *(const uint2*)o;
    if (e >= 4*WN) {
        #pragma unroll
        for (int j = 0; j < 4; j++) {
            int d = (rel + j) >> 7, ee = (rel + j) & 127;
            MbT[ee*128 + d] = o[j];
        }
    }
}

// QKV projection, split-K=4: X[8192,2048]fp32 @ Wqkv[384,2048]^T
// each kb-slice stores its own bf16 partial slab (no atomics)
__global__ __launch_bounds__(256, 3) void k_gemm_qkv(
    const float* __restrict__ X, const unsigned short* __restrict__ W,
    unsigned short* __restrict__ AccB)
{
    __shared__ unsigned short lA[128*64];
    __shared__ unsigned short lB[128*64];
    const int tid = threadIdx.x;
    const int row0 = blockIdx.x * 128;
    const int ct   = blockIdx.y;
    const int n0   = ct * 128;
    const int kb   = blockIdx.z * 512;
    const int wave = tid >> 6, lane = tid & 63;
    const int wm = wave >> 1, wn = wave & 1;
    const int quad = lane >> 4, lr = lane & 15;

    f32x4 acc[4][4]; zaccg(acc);

    for (int kt = kb; kt < kb + 512; kt += 64) {
        #pragma unroll
        for (int i = 0; i < 4; i++) {            // A: fp32 -> bf16 inline
            int s = tid + i*256; int r = s >> 3, kc = s & 7;
            const float* gp = X + (size_t)(row0 + r)*Hsz + kt + kc*8;
            float4 a0 = *(const float4*)gp;
            float4 a1 = *(const float4*)(gp + 4);
            const float* f0 = (const float*)&a0;
            const float* f1 = (const float*)&a1;
            unsigned short tmp[8];
            #pragma unroll
            for (int j = 0; j < 4; j++) { tmp[j] = f2b(f0[j]); tmp[4+j] = f2b(f1[j]); }
            *(uint4*)&lA[swzR(r, kc, 128)] = *(const uint4*)tmp;
        }
        #pragma unroll
        for (int i = 0; i < 4; i++) {            // B: bf16 16B copy
            int s = tid + i*256; int r = s >> 3, kc = s & 7;
            *(uint4*)&lB[swzR(r, kc, 128)] = *(const uint4*)(W + (size_t)(n0 + r)*Hsz + kt + kc*8);
        }
        __syncthreads();
        mmg<2,4>(lA, lB, acc, wm, wn, quad, lr);
        __syncthreads();
    }

    unsigned short* base = AccB + ((size_t)(blockIdx.z*3 + ct))*Nrow*128;
    #pragma unroll
    for (int mb = 0; mb < 4; mb++)
        #pragma unroll
        for (int nb = 0; nb < 4; nb++)
            #pragma unroll
            for (int rg = 0; rg < 4; rg++) {
                int s_ = wm*64 + mb*16 + quad*4 + rg;
                int e_ = wn*64 + nb*16 + lr;
                base[(size_t)(row0 + s_)*128 + e_] = f2b(acc[mb][nb][rg]);
            }
}

// epilogue: sum 4 bf16 partial slabs -> sigma (q,k) -> bf16 Q/K/V
__global__ void k_qkv_epi(const unsigned short* __restrict__ AccB,
                          unsigned short* __restrict__ Qb,
                          unsigned short* __restrict__ Kb, unsigned short* __restrict__ Vb)
{
    int gid = blockIdx.x*256 + threadIdx.x;      // 393216 threads, 8 elems each
    int ct = gid / (Nrow*16);
    int off = (gid - ct*Nrow*16) * 8;
    float vs[8];
    #pragma unroll
    for (int j = 0; j < 8; j++) vs[j] = 0.f;
    #pragma unroll
    for (int s = 0; s < 4; s++) {
        uint4 u = *(const uint4*)&AccB[((size_t)s*3 + ct)*Nrow*128 + off];
        const unsigned short* us = (const unsigned short*)&u;
        #pragma unroll
        for (int j = 0; j < 8; j++) vs[j] += b2f(us[j]);
    }
    unsigned short o[8];
    if (ct < 2) {
        #pragma unroll
        for (int j = 0; j < 8; j++) o[j] = f2b(sig_elu(vs[j]));
    } else {
        #pragma unroll
        for (int j = 0; j < 8; j++) o[j] = f2b(vs[j]);
    }
    unsigned short* dst = (ct == 0) ? Qb : (ct == 1 ? Kb : Vb);
    *(uint4*)&dst[off] = *(const uint4*)o;
}

// per (chunk, e-half): vret=(K̃M)/(K̃·z+eps); Mpart[:,eh]=K̃^T(V-vret)[:,eh];
// KVT[:,dh]=V^T K̃[:,dh]; ksum (h==0 only)
__global__ __launch_bounds__(256, 1) void k_delta_kv(
    const unsigned short* __restrict__ Kb, const unsigned short* __restrict__ Vb,
    const unsigned short* __restrict__ MbT, const float* __restrict__ z,
    float* __restrict__ KVT, float* __restrict__ ksum, float* __restrict__ Mpart)
{
    __shared__ unsigned short b0[128*128];
    __shared__ unsigned short b1[64*128];
    __shared__ float den[128];
    const int tid = threadIdx.x;
    const int c = blockIdx.x, t0 = c*128;
    const int h = blockIdx.y, e0 = h*64;
    const int wave = tid >> 6, lane = tid & 63;
    const int wm = wave >> 1, wn = wave & 1, quad = lane >> 4, lr = lane & 15;

    stage_dir<128>(b0, Kb + (size_t)t0*Dsz, Dsz, tid);   // K̃ (A)
    stage_dir<64>(b1, MbT + (size_t)e0*128, 128, tid);    // M^T e-half (B)
    __syncthreads();                                      // #1

    f32x4 acc1[4][2]; zaccg(acc1);
    mmg<4,2>(b0, b1, acc1, wm, wn, quad, lr);             // vret_num[t][e_local]

    if (tid < 128) {                                      // den[t] = K̃[t]·z + eps
        float p = 0.f;
        for (int d = 0; d < 128; d++)
            p += b2f(b0[swzR(tid, d >> 3, 128) + (d & 7)]) * z[d];
        den[tid] = p + EPSF;
    }
    __syncthreads();                                      // #2

    stage_T128(b0, Kb + (size_t)t0*Dsz, Dsz, tid);        // K̃^T (A: elem (d,t))
    #pragma unroll
    for (int mb = 0; mb < 4; mb++)                         // b1 <- W = V - vret (B: elem (e_l,t))
        #pragma unroll
        for (int nb = 0; nb < 2; nb++)
            #pragma unroll
            for (int rg = 0; rg < 4; rg++) {
                int s_ = wm*64 + mb*16 + quad*4 + rg;
                int el = wn*32 + nb*16 + lr;
                float v = b2f(Vb[(size_t)(t0 + s_)*Dsz + e0 + el]);
                float w = v - acc1[mb][nb][rg] / den[s_];
                b1[swzR(el, s_ >> 3, 64) + (s_ & 7)] = f2b(w);
            }
    __syncthreads();                                      // #3

    if (h == 0 && tid < 128) {                            // ksum[d] = sum_t K̃[t][d]
        float p = 0.f;
        for (int t = 0; t < 128; t++)
            p += b2f(b0[swzR(tid, t >> 3, 128) + (t & 7)]);
        ksum[(size_t)c*128 + tid] = p;
    }
    f32x4 acc2[4][2]; zaccg(acc2);
    mmg<4,2>(b0, b1, acc2, wm, wn, quad, lr);             // Mpart[d][e_local]
    #pragma unroll
    for (int mb = 0; mb < 4; mb++)
        #pragma unroll
        for (int nb = 0; nb < 2; nb++)
            #pragma unroll
            for (int rg = 0; rg < 4; rg++) {
                int d_ = wm*64 + mb*16 + quad*4 + rg;
                int el = wn*32 + nb*16 + lr;
                Mpart[(size_t)c*16384 + (size_t)d_*128 + e0 + el] = acc2[mb][nb][rg];
            }
    __syncthreads();                                      // #4

    stage_T128(b0, Vb + (size_t)t0*Dsz, Dsz, tid);        // V^T (A: elem (e,t))
    stage_T64(b1, Kb + (size_t)t0*Dsz, Dsz, e0, tid);     // K̃ d-half (B: elem (d_l,t))
    __syncthreads();                                      // #5

    f32x4 acc3[4][2]; zaccg(acc3);
    mmg<4,2>(b0, b1, acc3, wm, wn, quad, lr);             // KVT[e][d_local]
    #pragma unroll
    for (int mb = 0; mb < 4; mb++)
        #pragma unroll
        for (int nb = 0; nb < 2; nb++)
            #pragma unroll
            for (int rg = 0; rg < 4; rg++) {
                int e_ = wm*64 + mb*16 + quad*4 + rg;
                int dl_ = wn*32 + nb*16 + lr;
                KVT[(size_t)c*16384 + (size_t)e_*128 + e0 + dl_] = acc3[mb][nb][rg];
            }
}

// fused: exclusive chunk-prefix of KVT (-> bf16) and ksum, plus final M_new / z_new
__global__ void k_scan_final(
    const float* __restrict__ KVT, const float* __restrict__ ksum,
    const float* __restrict__ M, const float* __restrict__ z,
    const float* __restrict__ Mpart, unsigned short* __restrict__ KVTp,
    float* __restrict__ kpre, float* __restrict__ omz)
{
    int idx = blockIdx.x*256 + threadIdx.x;
    if (idx < 32768) {                       // KVT scan (per batch)
        int batch = idx >> 14, ed = idx & 16383;
        float a = 0.f;
        #pragma unroll 8
        for (int i = 0; i < CPB; i++) {
            size_t cc = (size_t)(batch*CPB + i);
            KVTp[cc*16384 + ed] = f2b(a);
            a += KVT[cc*16384 + ed];
        }
    } else if (idx < 33024) {                // ksum scan
        int j = idx - 32768; int batch = j >> 7, d = j & 127;
        float a = 0.f;
        #pragma unroll 8
        for (int i = 0; i < CPB; i++) {
            int cc = batch*CPB + i;
            kpre[cc*128 + d] = a;
            a += ksum[cc*128 + d];
        }
    } else if (idx < 49408) {                // M_new
        int m = idx - 33024;
        float a = M[m];
        #pragma unroll 8
        for (int cc = 0; cc < NCH; cc++) a += Mpart[(size_t)cc*16384 + m];
        omz[m] = a;
    } else if (idx < 49536) {                // z_new
        int d = idx - 49408;
        float a = z[d];
        #pragma unroll 8
        for (int cc = 0; cc < NCH; cc++) a += ksum[cc*128 + d];
        omz[16384 + d] = a;
    }
}

// fused attention per (chunk, e-half): memory-retrieve + inter-chunk + intra causal -> P bf16
__global__ __launch_bounds__(256, 1) void k_attn(
    const unsigned short* __restrict__ Qb, const unsigned short* __restrict__ KVTp,
    const float* __restrict__ kpre, const unsigned short* __restrict__ MbT,
    const float* __restrict__ z, const float* __restrict__ gate,
    const unsigned short* __restrict__ Kb, const unsigned short* __restrict__ Vb,
    unsigned short* __restrict__ P)
{
    __shared__ unsigned short b0[128*128];
    __shared__ unsigned short b1[128*128];   // also used as two 64-row halves
    __shared__ float dmem[128], dl[128], rs[128];
    const int tid = threadIdx.x;
    const int c = blockIdx.x, t0 = c*128;
    const int h = blockIdx.y, e0 = h*64;
    const int wave = tid >> 6, lane = tid & 63;
    const int wm = wave >> 1, wn = wave & 1, quad = lane >> 4, lr = lane & 15;
    unsigned short* b1lo = b1;
    unsigned short* b1hi = b1 + 64*128;

    if (tid < 128) rs[tid] = 0.f;
    stage_dir<128>(b0, Qb + (size_t)t0*Dsz, Dsz, tid);          // Q̃ (A)
    stage_dir<64>(b1lo, MbT + (size_t)e0*128, 128, tid);        // M^T e-half (B)
    stage_dir<64>(b1hi, KVTp + (size_t)c*16384 + (size_t)e0*128, 128, tid); // KVpre e-half (B)
    __syncthreads();                                            // #1

    if (tid < 128) {                                            // dmem = Q̃·z + eps
        float p = 0.f;
        for (int d = 0; d < 128; d++)
            p += b2f(b0[swzR(tid, d >> 3, 128) + (d & 7)]) * z[d];
        dmem[tid] = p + EPSF;
    } else {                                                    // dl = Q̃·kpre
        int s_ = tid - 128; float p = 0.f;
        for (int d = 0; d < 128; d++)
            p += b2f(b0[swzR(s_, d >> 3, 128) + (d & 7)]) * kpre[c*128 + d];
        dl[s_] = p;
    }
    f32x4 accM[4][2]; zaccg(accM);
    mmg<4,2>(b0, b1lo, accM, wm, wn, quad, lr);                 // mem_num[t][e_local]
    f32x4 accN[4][2]; zaccg(accN);
    mmg<4,2>(b0, b1hi, accN, wm, wn, quad, lr);                 // inter numerator
    __syncthreads();                                            // #2

    float g = 1.f / (1.f + expf(-gate[0]));
    f32x4 base[4][2];
    #pragma unroll
    for (int mb = 0; mb < 4; mb++)
        #pragma unroll
        for (int nb = 0; nb < 2; nb++)
            #pragma unroll
            for (int rg = 0; rg < 4; rg++) {
                int s_ = wm*64 + mb*16 + quad*4 + rg;
                base[mb][nb][rg] = g * accM[mb][nb][rg] / dmem[s_];
            }
    stage_dir<128>(b1, Kb + (size_t)t0*Dsz, Dsz, tid);          // K̃ full (B for S)
    __syncthreads();                                            // #3

    f32x4 accS[4][4]; zaccg(accS);
    mmg<4,4>(b0, b1, accS, wm, wn, quad, lr);                   // S[s][t]
    __syncthreads();                                            // #4

    #pragma unroll
    for (int mb = 0; mb < 4; mb++)                              // mask + rowsum + S -> b0 (A)
        #pragma unroll
        for (int rg = 0; rg < 4; rg++) {
            int s_ = wm*64 + mb*16 + quad*4 + rg;
            float part = 0.f;
            #pragma unroll
            for (int nb = 0; nb < 4; nb++) {
                int t_ = wn*64 + nb*16 + lr;
                float v = (t_ <= s_) ? accS[mb][nb][rg] : 0.f;
                part += v;
                b0[swzR(s_, t_ >> 3, 128) + (t_ & 7)] = f2b(v);
            }
            #pragma unroll
            for (int m = 1; m < 16; m <<= 1) part += __shfl_xor(part, m, 64);
            if (lr == 0) atomicAdd(&rs[s_], part);
        }
    stage_T64(b1lo, Vb + (size_t)t0*Dsz, Dsz, e0, tid);         // V^T e-half (B)
    __syncthreads();                                            // #5

    f32x4 accV[4][2]; zaccg(accV);
    mmg<4,2>(b0, b1lo, accV, wm, wn, quad, lr);                 // intra numerator

    #pragma unroll
    for (int mb = 0; mb < 4; mb++)
        #pragma unroll
        for (int nb = 0; nb < 2; nb++)
            #pragma unroll
            for (int rg = 0; rg < 4; rg++) {
                int s_ = wm*64 + mb*16 + quad*4 + rg;
                int el = wn*32 + nb*16 + lr;
                float num = accN[mb][nb][rg] + accV[mb][nb][rg];
                float dd  = dl[s_] + rs[s_] + EPSF;
                float val = base[mb][nb][rg] + (1.f - g) * num / dd;
                P[(size_t)(t0 + s_)*Dsz + e0 + el] = f2b(val);
            }
}

// out = P[8192,128] @ Wo[2048,128]^T, fp32
__global__ __launch_bounds__(256, 2) void k_gemm_out(
    const unsigned short* __restrict__ P, const unsigned short* __restrict__ Wo,
    float* __restrict__ out)
{
    __shared__ unsigned short b0[128*128];
    __shared__ unsigned short b1[128*128];
    const int tid = threadIdx.x;
    const int row0 = blockIdx.x*128, n0 = blockIdx.y*128;
    const int wave = tid >> 6, lane = tid & 63;
    const int wm = wave >> 1, wn = wave & 1, quad = lane >> 4, lr = lane & 15;

    stage_dir<128>(b0, P  + (size_t)row0*Dsz, Dsz, tid);
    stage_dir<128>(b1, Wo + (size_t)n0*Dsz,  Dsz, tid);
    __syncthreads();

    f32x4 acc[4][4]; zaccg(acc);
    mmg<4,4>(b0, b1, acc, wm, wn, quad, lr);
    #pragma unroll
    for (int mb = 0; mb < 4; mb++)
        #pragma unroll
        for (int nb = 0; nb < 4; nb++)
            #pragma unroll
            for (int rg = 0; rg < 4; rg++) {
                int s_ = wm*64 + mb*16 + quad*4 + rg;
                int e_ = wn*64 + nb*16 + lr;
                out[(size_t)(row0 + s_)*Hsz + n0 + e_] = acc[mb][nb][rg];
            }
}

// ---------------- launcher ----------------
extern "C" void kernel_launch(void* const* d_in, const int* in_sizes, int n_in,
                              void* d_out, int out_size, void* d_ws, size_t ws_size,
                              hipStream_t stream)
{
    const float* X    = (const float*)d_in[0];
    const float* wq   = (const float*)d_in[1];
    const float* wk   = (const float*)d_in[2];
    const float* wv   = (const float*)d_in[3];
    const float* wo   = (const float*)d_in[4];
    const float* gate = (const float*)d_in[5];
    const float* M    = (const float*)d_in[6];
    const float* z    = (const float*)d_in[7];

    char* ws = (char*)d_ws;
    unsigned short* Wfull = (unsigned short*)(ws + WQKV_OFF);   // Wqkv|Wo contiguous
    unsigned short* Wo_b  = (unsigned short*)(ws + WO_OFF);
    unsigned short* MbT   = (unsigned short*)(ws + MBT_OFF);
    unsigned short* Qb    = (unsigned short*)(ws + QB_OFF);
    unsigned short* Kb    = (unsigned short*)(ws + KB_OFF);
    unsigned short* Vb    = (unsigned short*)(ws + VB_OFF);
    unsigned short* Pb    = (unsigned short*)(ws + PB_OFF);
    unsigned short* AccB  = (unsigned short*)(ws + ACC_OFF);
    float* KVT   = (float*)(ws + KVT_OFF);
    unsigned short* KVTp = (unsigned short*)(ws + KVTP_OFF);
    float* Mpart = (float*)(ws + MPART_OFF);
    float* ksum  = (float*)(ws + KSUM_OFF);
    float* kpre  = (float*)(ws + KPRE_OFF);

    float* outp   = (float*)d_out;
    float* out_mz = outp + (size_t)Nrow*Hsz;

    k_cvt_w<<<((4*WN + 16384)/4 + 255)/256, 256, 0, stream>>>(wq, wk, wv, wo, M, Wfull, MbT);
    k_gemm_qkv<<<dim3(Nrow/128, 3, 4), 256, 0, stream>>>(X, Wfull, AccB);
    k_qkv_epi<<<(3*Nrow*16)/256, 256, 0, stream>>>(AccB, Qb, Kb, Vb);
    k_delta_kv<<<dim3(NCH, 2), 256, 0, stream>>>(Kb, Vb, MbT, z, KVT, ksum, Mpart);
    k_scan_final<<<194, 256, 0, stream>>>(KVT, ksum, M, z, Mpart, KVTp, kpre, out_mz);
    k_attn<<<dim3(NCH, 2), 256, 0, stream>>>(Qb, KVTp, kpre, MbT, z, gate, Kb, Vb, Pb);
    k_gemm_out<<<dim3(Nrow/128, Hsz/128), 256, 0, stream>>>(Pb, Wo_b, outp);
}

// Round 4
// 188.857 us; speedup vs baseline: 1.4764x; 1.1005x over previous
//
#include <hip/hip_runtime.h>
#include <hip/hip_bf16.h>
#include <math.h>

#define DI __device__ __forceinline__

typedef __bf16 bf16x8 __attribute__((ext_vector_type(8)));
typedef float  f32x4  __attribute__((ext_vector_type(4)));

static constexpr int   Bsz  = 2, Ssz = 4096, Hsz = 2048, Dsz = 128;
static constexpr int   Nrow = Bsz * Ssz;     // 8192
static constexpr int   NCH  = Nrow / 128;    // 64 chunks
static constexpr int   CPB  = Ssz / 128;     // 32 chunks per batch
static constexpr int   WN   = Dsz * Hsz;     // 262144
static constexpr float EPSF = 1e-6f;

// ---------------- workspace layout (bytes) ----------------
static constexpr size_t WQKV_OFF = 0;                            // bf16 [384][2048]
static constexpr size_t WO_OFF   = (size_t)3*WN*2;               // bf16 [2048][128]
static constexpr size_t MB_OFF   = WO_OFF + (size_t)WN*2;        // bf16 [128][128] (cvt spill)
static constexpr size_t MBT_OFF  = MB_OFF + 32768;               // bf16 M^T [128][128]
static constexpr size_t QB_OFF   = MBT_OFF + 32768;              // bf16 [8192][128]
static constexpr size_t KB_OFF   = QB_OFF + (size_t)Nrow*Dsz*2;
static constexpr size_t VB_OFF   = KB_OFF + (size_t)Nrow*Dsz*2;
static constexpr size_t PB_OFF   = VB_OFF + (size_t)Nrow*Dsz*2;
static constexpr size_t ACC_OFF  = PB_OFF + (size_t)Nrow*Dsz*2;  // bf16 [4][3][8192][128] = 25.2MB
// --- aliased into ACC region (dead after k_qkv_epi) ---
static constexpr size_t KV_OFF   = ACC_OFF;                      // f32 [64][128d][128e] 4MB
static constexpr size_t KVP_OFF  = ACC_OFF + (size_t)4*1024*1024;// bf16 [64][128d][128e] 2MB
static constexpr size_t MPART_OFF= ACC_OFF + (size_t)6*1024*1024;// f32 [64][128][128] 4MB
static constexpr size_t KSUM_OFF = ACC_OFF + (size_t)10*1024*1024;// f32 [64][128]
static constexpr size_t KPRE_OFF = KSUM_OFF + 32768;             // f32 [64][128]

// ---------------- helpers ----------------
DI float b2f(unsigned short u) {
    union { float f; unsigned int i; } x; x.i = ((unsigned int)u) << 16; return x.f;
}
DI unsigned short f2b(float f) {
    __bf16 h = (__bf16)f; return __builtin_bit_cast(unsigned short, h);
}
DI float sig_elu(float x) { return x > 0.f ? x + 1.f : expf(x); }

DI f32x4 MFMA(bf16x8 a, bf16x8 b, f32x4 c) {
    return __builtin_amdgcn_mfma_f32_16x16x32_bf16(a, b, c, 0, 0, 0);
}
template<int NB>
DI void zaccg(f32x4 (&acc)[4][NB]) {
    f32x4 zz = {0.f, 0.f, 0.f, 0.f};
    #pragma unroll
    for (int i = 0; i < 4; i++)
        #pragma unroll
        for (int j = 0; j < NB; j++) acc[i][j] = zz;
}

// async 16B global -> LDS (DMA, bypasses VGPRs). LDS dst = wave-uniform base + lane*16.
DI void gll16(const void* g, void* l) {
    __builtin_amdgcn_global_load_lds((const __attribute__((address_space(1))) void*)g,
                                     (__attribute__((address_space(3))) void*)l, 16, 0, 0);
}

// swizzled chunk offset (ushorts) of 8-elem chunk (r, kc) in a VALU-staged operand
// tile with R rows (XOR banking)
DI int swzR(int r, int kc, int R) { return (kc*R + (r ^ (kc & 7))) * 8; }

// generic matmul out of swzR-layout LDS: A 128 rows, B NB*32 rows
template<int NKS, int NB>
DI void mmg(const unsigned short* A, const unsigned short* Bm, f32x4 (&acc)[4][NB],
            int wm, int wn, int quad, int lr) {
    #pragma unroll
    for (int ks = 0; ks < NKS; ks++) {
        bf16x8 a[4], b[NB];
        #pragma unroll
        for (int mb = 0; mb < 4; mb++)
            a[mb] = *(const bf16x8*)&A[swzR(wm*64 + mb*16 + lr, ks*4 + quad, 128)];
        #pragma unroll
        for (int nb = 0; nb < NB; nb++)
            b[nb] = *(const bf16x8*)&Bm[swzR(wn*(NB*16) + nb*16 + lr, ks*4 + quad, NB*32)];
        #pragma unroll
        for (int mb = 0; mb < 4; mb++)
            #pragma unroll
            for (int nb = 0; nb < NB; nb++)
                acc[mb][nb] = MFMA(a[mb], b[nb], acc[mb][nb]);
    }
}

// row-major [R][128] bf16 tile -> swzR operand layout (VALU path)
template<int R>
DI void stage_dir(unsigned short* dst, const unsigned short* src, int src_ld, int tid) {
    #pragma unroll
    for (int i = 0; i < R/16; i++) {
        int s = tid + i*256; int r = s >> 4, kc = s & 15;
        *(uint4*)&dst[swzR(r, kc, R)] = *(const uint4*)(src + (size_t)r*src_ld + kc*8);
    }
}

// transposed staging (full 128): operand elem (r=col, k=row) <- src[row][col]
DI void stage_T128(unsigned short* dst, const unsigned short* src, int src_ld, int tid) {
    #pragma unroll
    for (int i = 0; i < 8; i++) {
        int s = tid + i*256;
        int rw = (s & 15) + ((s >> 8) << 4);
        int c0 = ((s >> 4) & 15) * 8;
        unsigned short tmp[8];
        *(uint4*)tmp = *(const uint4*)(src + (size_t)rw*src_ld + c0);
        #pragma unroll
        for (int j = 0; j < 8; j++)
            dst[swzR(c0 + j, rw >> 3, 128) + (rw & 7)] = tmp[j];
    }
}

// transposed staging into 32-row operand: elem (r=col-colOff, k=row) <- src[row][colOff+col]
DI void stage_T32(unsigned short* dst, const unsigned short* src, int src_ld, int colOff, int tid) {
    #pragma unroll
    for (int i = 0; i < 2; i++) {
        int s = tid + i*256;                     // 0..511
        int rw = (s & 15) + ((s >> 6) << 4);     // 0..127
        int c0 = ((s >> 4) & 3) * 8;             // 0..24
        unsigned short tmp[8];
        *(uint4*)tmp = *(const uint4*)(src + (size_t)rw*src_ld + colOff + c0);
        #pragma unroll
        for (int j = 0; j < 8; j++)
            dst[swzR(c0 + j, rw >> 3, 32) + (rw & 7)] = tmp[j];
    }
}

// ---------------- kernels ----------------

// fused weight conversion: wq|wk|wv -> Wqkv, wo -> Wo, M -> (spill) and MbT
__global__ void k_cvt_w(const float* __restrict__ wq, const float* __restrict__ wk,
                        const float* __restrict__ wv, const float* __restrict__ wo,
                        const float* __restrict__ M, unsigned short* __restrict__ dst,
                        unsigned short* __restrict__ MbT)
{
    int gid = blockIdx.x*256 + threadIdx.x;
    if (gid >= (4*WN + 16384)/4) return;
    int e = gid*4;
    const float* src; int rel;
    if      (e < WN)     { src = wq; rel = e; }
    else if (e < 2*WN)   { src = wk; rel = e - WN; }
    else if (e < 3*WN)   { src = wv; rel = e - 2*WN; }
    else if (e < 4*WN)   { src = wo; rel = e - 3*WN; }
    else                 { src = M;  rel = e - 4*WN; }
    float4 v = *(const float4*)(src + rel);
    const float* vf = (const float*)&v;
    unsigned short o[4];
    #pragma unroll
    for (int j = 0; j < 4; j++) o[j] = f2b(vf[j]);
    *(uint2*)&dst[e] = *(const uint2*)o;
    if (e >= 4*WN) {
        #pragma unroll
        for (int j = 0; j < 4; j++) {
            int d = (rel + j) >> 7, ee = (rel + j) & 127;
            MbT[ee*128 + d] = o[j];
        }
    }
}

// QKV projection, split-K=4: X[8192,2048]fp32 @ Wqkv[384,2048]^T
// global_load_lds staging (XOR source-permuted), consumer-side fp32->bf16 cvt
__global__ __launch_bounds__(256, 3) void k_gemm_qkv(
    const float* __restrict__ X, const unsigned short* __restrict__ W,
    unsigned short* __restrict__ AccB)
{
    __shared__ float          lA[128*64];   // fp32, chunk p=(r*16 + (kc^(r&15))), 16B chunks
    __shared__ unsigned short lB[128*64];   // bf16, chunk p=(r*8  + (kc^(r&7)))
    const int tid = threadIdx.x;
    const int row0 = blockIdx.x * 128;
    const int ct   = blockIdx.y;
    const int n0   = ct * 128;
    const int kb   = blockIdx.z * 512;
    const int wave = tid >> 6, lane = tid & 63;
    const int wm = wave >> 1, wn = wave & 1;
    const int quad = lane >> 4, lr = lane & 15;

    f32x4 acc[4][4]; zaccg(acc);

    for (int kt = kb; kt < kb + 512; kt += 64) {
        #pragma unroll
        for (int i = 0; i < 8; i++) {        // A: 2048 chunks of 4 fp32
            int p = tid + i*256; int r = p >> 4; int kc = (p & 15) ^ (r & 15);
            gll16(X + (size_t)(row0 + r)*Hsz + kt + kc*4, &lA[p*4]);
        }
        #pragma unroll
        for (int i = 0; i < 4; i++) {        // B: 1024 chunks of 8 bf16
            int p = tid + i*256; int r = p >> 3; int kc = (p & 7) ^ (r & 7);
            gll16(W + (size_t)(n0 + r)*Hsz + kt + kc*8, &lB[p*8]);
        }
        __syncthreads();
        #pragma unroll
        for (int ks = 0; ks < 2; ks++) {
            bf16x8 a[4], b[4];
            #pragma unroll
            for (int mb = 0; mb < 4; mb++) {
                int r = wm*64 + mb*16 + lr;
                int c0 = (ks*4 + quad)*2;
                f32x4 u0 = *(const f32x4*)&lA[(r*16 + ( c0      ^ (r & 15)))*4];
                f32x4 u1 = *(const f32x4*)&lA[(r*16 + ((c0 + 1) ^ (r & 15)))*4];
                bf16x8 t;
                #pragma unroll
                for (int j = 0; j < 4; j++) { t[j] = (__bf16)u0[j]; t[4+j] = (__bf16)u1[j]; }
                a[mb] = t;
            }
            #pragma unroll
            for (int nb = 0; nb < 4; nb++) {
                int r = wn*64 + nb*16 + lr;
                int c = (ks*4 + quad) ^ (r & 7);
                b[nb] = *(const bf16x8*)&lB[(r*8 + c)*8];
            }
            #pragma unroll
            for (int mb = 0; mb < 4; mb++)
                #pragma unroll
                for (int nb = 0; nb < 4; nb++)
                    acc[mb][nb] = MFMA(a[mb], b[nb], acc[mb][nb]);
        }
        __syncthreads();
    }

    unsigned short* base = AccB + ((size_t)(blockIdx.z*3 + ct))*Nrow*128;
    #pragma unroll
    for (int mb = 0; mb < 4; mb++)
        #pragma unroll
        for (int nb = 0; nb < 4; nb++)
            #pragma unroll
            for (int rg = 0; rg < 4; rg++) {
                int s_ = wm*64 + mb*16 + quad*4 + rg;
                int e_ = wn*64 + nb*16 + lr;
                base[(size_t)(row0 + s_)*128 + e_] = f2b(acc[mb][nb][rg]);
            }
}

// epilogue: sum 4 bf16 partial slabs -> sigma (q,k) -> bf16 Q/K/V
__global__ void k_qkv_epi(const unsigned short* __restrict__ AccB,
                          unsigned short* __restrict__ Qb,
                          unsigned short* __restrict__ Kb, unsigned short* __restrict__ Vb)
{
    int gid = blockIdx.x*256 + threadIdx.x;      // 393216 threads, 8 elems each
    int ct = gid / (Nrow*16);
    int off = (gid - ct*Nrow*16) * 8;
    float vs[8];
    #pragma unroll
    for (int j = 0; j < 8; j++) vs[j] = 0.f;
    #pragma unroll
    for (int s = 0; s < 4; s++) {
        uint4 u = *(const uint4*)&AccB[((size_t)s*3 + ct)*Nrow*128 + off];
        const unsigned short* us = (const unsigned short*)&u;
        #pragma unroll
        for (int j = 0; j < 8; j++) vs[j] += b2f(us[j]);
    }
    unsigned short o[8];
    if (ct < 2) {
        #pragma unroll
        for (int j = 0; j < 8; j++) o[j] = f2b(sig_elu(vs[j]));
    } else {
        #pragma unroll
        for (int j = 0; j < 8; j++) o[j] = f2b(vs[j]);
    }
    unsigned short* dst = (ct == 0) ? Qb : (ct == 1 ? Kb : Vb);
    *(uint4*)&dst[off] = *(const uint4*)o;
}

// per (chunk, e-quarter): vret=(K̃M)/(K̃·z+eps); Mpart[:,eq]=K̃^T(V-vret)[:,eq];
// KV[:,eq]=K̃^T V[:,eq]; ksum (eq==0 only). K̃^T staged once, reused as A twice.
__global__ __launch_bounds__(256, 2) void k_delta_kv(
    const unsigned short* __restrict__ Kb, const unsigned short* __restrict__ Vb,
    const unsigned short* __restrict__ MbT, const float* __restrict__ z,
    float* __restrict__ KV, float* __restrict__ ksum, float* __restrict__ Mpart)
{
    __shared__ unsigned short b0[128*128];   // K̃ then K̃^T
    __shared__ unsigned short b1a[32*128];   // M^T quarter, B
    __shared__ unsigned short b1b[32*128];   // W = V - vret, B
    __shared__ unsigned short b1c[32*128];   // V quarter, B
    __shared__ float den[128];
    const int tid = threadIdx.x;
    const int c = blockIdx.x, t0 = c*128;
    const int e0 = blockIdx.y * 32;
    const int wave = tid >> 6, lane = tid & 63;
    const int wm = wave >> 1, wn = wave & 1, quad = lane >> 4, lr = lane & 15;

    stage_dir<128>(b0, Kb + (size_t)t0*Dsz, Dsz, tid);   // K̃ (A)
    stage_dir<32>(b1a, MbT + (size_t)e0*128, 128, tid);  // M^T quarter (B)
    __syncthreads();                                     // #1

    f32x4 acc1[4][1]; zaccg(acc1);
    mmg<4,1>(b0, b1a, acc1, wm, wn, quad, lr);           // vret_num[t][el]

    if (tid < 128) {                                     // den[t] = K̃[t]·z + eps
        float p = 0.f;
        for (int d = 0; d < 128; d++)
            p += b2f(b0[swzR(tid, d >> 3, 128) + (d & 7)]) * z[d];
        den[tid] = p + EPSF;
    }
    __syncthreads();                                     // #2

    stage_T128(b0, Kb + (size_t)t0*Dsz, Dsz, tid);       // K̃^T (A: elem (d,t))
    stage_T32(b1c, Vb + (size_t)t0*Dsz, Dsz, e0, tid);   // V quarter (B: elem (el,t))
    #pragma unroll
    for (int mb = 0; mb < 4; mb++)                       // b1b <- W = V - vret
        #pragma unroll
        for (int rg = 0; rg < 4; rg++) {
            int s_ = wm*64 + mb*16 + quad*4 + rg;
            int el = wn*16 + lr;
            float v = b2f(Vb[(size_t)(t0 + s_)*Dsz + e0 + el]);
            float w = v - acc1[mb][0][rg] / den[s_];
            b1b[swzR(el, s_ >> 3, 32) + (s_ & 7)] = f2b(w);
        }
    __syncthreads();                                     // #3

    if (e0 == 0 && tid < 128) {                          // ksum[d] = sum_t K̃[t][d]
        float p = 0.f;
        for (int t = 0; t < 128; t++)
            p += b2f(b0[swzR(tid, t >> 3, 128) + (t & 7)]);
        ksum[(size_t)c*128 + tid] = p;
    }
    f32x4 acc2[4][1]; zaccg(acc2);
    mmg<4,1>(b0, b1b, acc2, wm, wn, quad, lr);           // Mpart[d][el]
    f32x4 acc3[4][1]; zaccg(acc3);
    mmg<4,1>(b0, b1c, acc3, wm, wn, quad, lr);           // KV[d][el]
    #pragma unroll
    for (int mb = 0; mb < 4; mb++)
        #pragma unroll
        for (int rg = 0; rg < 4; rg++) {
            int d_ = wm*64 + mb*16 + quad*4 + rg;
            int el = wn*16 + lr;
            Mpart[(size_t)c*16384 + (size_t)d_*128 + e0 + el] = acc2[mb][0][rg];
            KV[(size_t)c*16384 + (size_t)d_*128 + e0 + el]    = acc3[mb][0][rg];
        }
}

// fused: exclusive chunk-prefix of KV (-> bf16) and ksum, plus final M_new / z_new
__global__ void k_scan_final(
    const float* __restrict__ KV, const float* __restrict__ ksum,
    const float* __restrict__ M, const float* __restrict__ z,
    const float* __restrict__ Mpart, unsigned short* __restrict__ KVp,
    float* __restrict__ kpre, float* __restrict__ omz)
{
    int idx = blockIdx.x*256 + threadIdx.x;
    if (idx < 32768) {                       // KV scan (per batch)
        int batch = idx >> 14, ed = idx & 16383;
        float a = 0.f;
        #pragma unroll 8
        for (int i = 0; i < CPB; i++) {
            size_t cc = (size_t)(batch*CPB + i);
            KVp[cc*16384 + ed] = f2b(a);
            a += KV[cc*16384 + ed];
        }
    } else if (idx < 33024) {                // ksum scan
        int j = idx - 32768; int batch = j >> 7, d = j & 127;
        float a = 0.f;
        #pragma unroll 8
        for (int i = 0; i < CPB; i++) {
            int cc = batch*CPB + i;
            kpre[cc*128 + d] = a;
            a += ksum[cc*128 + d];
        }
    } else if (idx < 49408) {                // M_new
        int m = idx - 33024;
        float a = M[m];
        #pragma unroll 8
        for (int cc = 0; cc < NCH; cc++) a += Mpart[(size_t)cc*16384 + m];
        omz[m] = a;
    } else if (idx < 49536) {                // z_new
        int d = idx - 49408;
        float a = z[d];
        #pragma unroll 8
        for (int cc = 0; cc < NCH; cc++) a += ksum[cc*128 + d];
        omz[16384 + d] = a;
    }
}

// fused attention per (chunk, e-quarter): memory-retrieve + inter + intra causal -> P bf16
__global__ __launch_bounds__(256, 2) void k_attn(
    const unsigned short* __restrict__ Qb, const unsigned short* __restrict__ KVp,
    const float* __restrict__ kpre, const unsigned short* __restrict__ MbT,
    const float* __restrict__ z, const float* __restrict__ gate,
    const unsigned short* __restrict__ Kb, const unsigned short* __restrict__ Vb,
    unsigned short* __restrict__ P)
{
    __shared__ unsigned short b0[128*128];   // Q̃, then masked S
    __shared__ unsigned short b1[128*128];   // [Mq|KVpq] then K̃ then Vq
    __shared__ float dmem[128], dl[128], rs[128];
    const int tid = threadIdx.x;
    const int c = blockIdx.x, t0 = c*128;
    const int e0 = blockIdx.y * 32;
    const int wave = tid >> 6, lane = tid & 63;
    const int wm = wave >> 1, wn = wave & 1, quad = lane >> 4, lr = lane & 15;
    unsigned short* b1q0 = b1;
    unsigned short* b1q1 = b1 + 32*128;

    if (tid < 128) rs[tid] = 0.f;
    stage_dir<128>(b0, Qb + (size_t)t0*Dsz, Dsz, tid);          // Q̃ (A)
    stage_dir<32>(b1q0, MbT + (size_t)e0*128, 128, tid);        // M^T quarter (B)
    stage_T32(b1q1, KVp + (size_t)c*16384, 128, e0, tid);       // KVpre quarter (B: (el,d))
    __syncthreads();                                            // #1

    if (tid < 128) {                                            // dmem = Q̃·z + eps
        float p = 0.f;
        for (int d = 0; d < 128; d++)
            p += b2f(b0[swzR(tid, d >> 3, 128) + (d & 7)]) * z[d];
        dmem[tid] = p + EPSF;
    } else {                                                    // dl = Q̃·kpre
        int s_ = tid - 128; float p = 0.f;
        for (int d = 0; d < 128; d++)
            p += b2f(b0[swzR(s_, d >> 3, 128) + (d & 7)]) * kpre[c*128 + d];
        dl[s_] = p;
    }
    f32x4 accM[4][1]; zaccg(accM);
    mmg<4,1>(b0, b1q0, accM, wm, wn, quad, lr);                 // mem_num[t][el]
    f32x4 accN[4][1]; zaccg(accN);
    mmg<4,1>(b0, b1q1, accN, wm, wn, quad, lr);                 // inter numerator
    __syncthreads();                                            // #2

    float g = 1.f / (1.f + expf(-gate[0]));
    f32x4 base[4][1];
    #pragma unroll
    for (int mb = 0; mb < 4; mb++)
        #pragma unroll
        for (int rg = 0; rg < 4; rg++) {
            int s_ = wm*64 + mb*16 + quad*4 + rg;
            base[mb][0][rg] = g * accM[mb][0][rg] / dmem[s_];
        }
    stage_dir<128>(b1, Kb + (size_t)t0*Dsz, Dsz, tid);          // K̃ full (B for S)
    __syncthreads();                                            // #3

    f32x4 accS[4][4]; zaccg(accS);
    mmg<4,4>(b0, b1, accS, wm, wn, quad, lr);                   // S[s][t]
    __syncthreads();                                            // #4

    #pragma unroll
    for (int mb = 0; mb < 4; mb++)                              // mask + rowsum + S -> b0 (A)
        #pragma unroll
        for (int rg = 0; rg < 4; rg++) {
            int s_ = wm*64 + mb*16 + quad*4 + rg;
            float part = 0.f;
            #pragma unroll
            for (int nb = 0; nb < 4; nb++) {
                int t_ = wn*64 + nb*16 + lr;
                float v = (t_ <= s_) ? accS[mb][nb][rg] : 0.f;
                part += v;
                b0[swzR(s_, t_ >> 3, 128) + (t_ & 7)] = f2b(v);
            }
            #pragma unroll
            for (int m = 1; m < 16; m <<= 1) part += __shfl_xor(part, m, 64);
            if (lr == 0) atomicAdd(&rs[s_], part);
        }
    stage_T32(b1q0, Vb + (size_t)t0*Dsz, Dsz, e0, tid);         // V quarter (B: (el,t))
    __syncthreads();                                            // #5

    f32x4 accV[4][1]; zaccg(accV);
    mmg<4,1>(b0, b1q0, accV, wm, wn, quad, lr);                 // intra numerator

    #pragma unroll
    for (int mb = 0; mb < 4; mb++)
        #pragma unroll
        for (int rg = 0; rg < 4; rg++) {
            int s_ = wm*64 + mb*16 + quad*4 + rg;
            int el = wn*16 + lr;
            float num = accN[mb][0][rg] + accV[mb][0][rg];
            float dd  = dl[s_] + rs[s_] + EPSF;
            float val = base[mb][0][rg] + (1.f - g) * num / dd;
            P[(size_t)(t0 + s_)*Dsz + e0 + el] = f2b(val);
        }
}

// out = P[8192,128] @ Wo[2048,128]^T, fp32; global_load_lds staging (XOR-permuted)
__global__ __launch_bounds__(256, 2) void k_gemm_out(
    const unsigned short* __restrict__ P, const unsigned short* __restrict__ Wo,
    float* __restrict__ out)
{
    __shared__ unsigned short b0[128*128];   // chunk p = r*16 + (kc^(r&15))
    __shared__ unsigned short b1[128*128];
    const int tid = threadIdx.x;
    const int row0 = blockIdx.x*128, n0 = blockIdx.y*128;
    const int wave = tid >> 6, lane = tid & 63;
    const int wm = wave >> 1, wn = wave & 1, quad = lane >> 4, lr = lane & 15;

    #pragma unroll
    for (int i = 0; i < 8; i++) {
        int p = tid + i*256; int r = p >> 4; int kc = (p & 15) ^ (r & 15);
        gll16(P + (size_t)(row0 + r)*Dsz + kc*8, &b0[p*8]);
    }
    #pragma unroll
    for (int i = 0; i < 8; i++) {
        int p = tid + i*256; int r = p >> 4; int kc = (p & 15) ^ (r & 15);
        gll16(Wo + (size_t)(n0 + r)*Dsz + kc*8, &b1[p*8]);
    }
    __syncthreads();

    f32x4 acc[4][4]; zaccg(acc);
    #pragma unroll
    for (int ks = 0; ks < 4; ks++) {
        bf16x8 a[4], b[4];
        #pragma unroll
        for (int mb = 0; mb < 4; mb++) {
            int r = wm*64 + mb*16 + lr;
            a[mb] = *(const bf16x8*)&b0[(r*16 + ((ks*4 + quad) ^ (r & 15)))*8];
        }
        #pragma unroll
        for (int nb = 0; nb < 4; nb++) {
            int r = wn*64 + nb*16 + lr;
            b[nb] = *(const bf16x8*)&b1[(r*16 + ((ks*4 + quad) ^ (r & 15)))*8];
        }
        #pragma unroll
        for (int mb = 0; mb < 4; mb++)
            #pragma unroll
            for (int nb = 0; nb < 4; nb++)
                acc[mb][nb] = MFMA(a[mb], b[nb], acc[mb][nb]);
    }
    #pragma unroll
    for (int mb = 0; mb < 4; mb++)
        #pragma unroll
        for (int nb = 0; nb < 4; nb++)
            #pragma unroll
            for (int rg = 0; rg < 4; rg++) {
                int s_ = wm*64 + mb*16 + quad*4 + rg;
                int e_ = wn*64 + nb*16 + lr;
                out[(size_t)(row0 + s_)*Hsz + n0 + e_] = acc[mb][nb][rg];
            }
}

// ---------------- launcher ----------------
extern "C" void kernel_launch(void* const* d_in, const int* in_sizes, int n_in,
                              void* d_out, int out_size, void* d_ws, size_t ws_size,
                              hipStream_t stream)
{
    const float* X    = (const float*)d_in[0];
    const float* wq   = (const float*)d_in[1];
    const float* wk   = (const float*)d_in[2];
    const float* wv   = (const float*)d_in[3];
    const float* wo   = (const float*)d_in[4];
    const float* gate = (const float*)d_in[5];
    const float* M    = (const float*)d_in[6];
    const float* z    = (const float*)d_in[7];

    char* ws = (char*)d_ws;
    unsigned short* Wfull = (unsigned short*)(ws + WQKV_OFF);
    unsigned short* Wo_b  = (unsigned short*)(ws + WO_OFF);
    unsigned short* MbT   = (unsigned short*)(ws + MBT_OFF);
    unsigned short* Qb    = (unsigned short*)(ws + QB_OFF);
    unsigned short* Kb    = (unsigned short*)(ws + KB_OFF);
    unsigned short* Vb    = (unsigned short*)(ws + VB_OFF);
    unsigned short* Pb    = (unsigned short*)(ws + PB_OFF);
    unsigned short* AccB  = (unsigned short*)(ws + ACC_OFF);
    float* KV    = (float*)(ws + KV_OFF);
    unsigned short* KVp = (unsigned short*)(ws + KVP_OFF);
    float* Mpart = (float*)(ws + MPART_OFF);
    float* ksum  = (float*)(ws + KSUM_OFF);
    float* kpre  = (float*)(ws + KPRE_OFF);

    float* outp   = (float*)d_out;
    float* out_mz = outp + (size_t)Nrow*Hsz;

    k_cvt_w<<<((4*WN + 16384)/4 + 255)/256, 256, 0, stream>>>(wq, wk, wv, wo, M, Wfull, MbT);
    k_gemm_qkv<<<dim3(Nrow/128, 3, 4), 256, 0, stream>>>(X, Wfull, AccB);
    k_qkv_epi<<<(3*Nrow*16)/256, 256, 0, stream>>>(AccB, Qb, Kb, Vb);
    k_delta_kv<<<dim3(NCH, 4), 256, 0, stream>>>(Kb, Vb, MbT, z, KV, ksum, Mpart);
    k_scan_final<<<194, 256, 0, stream>>>(KV, ksum, M, z, Mpart, KVp, kpre, out_mz);
    k_attn<<<dim3(NCH, 4), 256, 0, stream>>>(Qb, KVp, kpre, MbT, z, gate, Kb, Vb, Pb);
    k_gemm_out<<<dim3(Nrow/128, Hsz/128), 256, 0, stream>>>(Pb, Wo_b, outp);
}